// Round 4
// baseline (427.349 us; speedup 1.0000x reference)
//
#include <hip/hip_runtime.h>

#define S_LEN 4096
#define D_MODEL 1024
#define NHEAD 16
#define DK 64
#define HID 2730
#define HIDP 2880
#define QKV_LD 3072

typedef unsigned short u16;
typedef unsigned int u32;
typedef __bf16 bf16x8 __attribute__((ext_vector_type(8)));
typedef float f32x4 __attribute__((ext_vector_type(4)));

#define MFMA16 __builtin_amdgcn_mfma_f32_16x16x32_bf16
// raw v_exp_f32 (2^x): scores bounded (|s| < ~30), no OCML guard code needed
#define EXP2 __builtin_amdgcn_exp2f

__device__ __forceinline__ float b2f(u16 u) {
    return __builtin_bit_cast(float, (u32)u << 16);
}
__device__ __forceinline__ u16 f2b(float f) {
    u32 u = __builtin_bit_cast(u32, f);
    u += 0x7FFF + ((u >> 16) & 1);
    return (u16)(u >> 16);
}
// pack two f32 -> two bf16 (truncate) in one v_perm_b32
__device__ __forceinline__ u32 pk_trunc(float lo, float hi) {
    return __builtin_amdgcn_perm(__builtin_bit_cast(u32, hi),
                                 __builtin_bit_cast(u32, lo), 0x07060302u);
}
// async global->LDS, 16B per lane; dest must be wave-uniform base + lane*16
__device__ __forceinline__ void gll16(const u16* g, u16* l) {
    __builtin_amdgcn_global_load_lds(
        (__attribute__((address_space(1))) void*)(g),
        (__attribute__((address_space(3))) void*)(l),
        16, 0, 0);
}

// ---------------------------------------------------------------------------
// Prep: 7 weight transposes (fp32->bf16, zero-pad) + rmsnorm(x, ln1) in ONE
// launch. Flat grid, 256-thread blocks. Blocks 0..12735 = tcast segments;
// blocks 12736..16831 = rmsnorm rows.  (HIDP = 2880 = 30*96)
// ---------------------------------------------------------------------------
__global__ __launch_bounds__(256)
void prep_k(const float* s0, const float* s1, const float* s2,
            const float* s3, const float* s4, const float* s5,
            const float* s6, u16* d0, u16* d1, u16* d2, u16* d3,
            u16* d4, u16* d5, u16* d6,
            const float* __restrict__ x, const float* __restrict__ ln1,
            u16* __restrict__ hb) {
    __shared__ float t[32][33];
    __shared__ float red[4];
    const int bid = blockIdx.x;
    const int tid = threadIdx.x;

    if (bid >= 12736) {   // ---- rmsnorm path ----
        const int row = bid - 12736;
        const float4 v = ((const float4*)(x + (size_t)row * D_MODEL))[tid];
        float ss = v.x * v.x + v.y * v.y + v.z * v.z + v.w * v.w;
        for (int o = 32; o; o >>= 1) ss += __shfl_down(ss, o);
        if ((tid & 63) == 0) red[tid >> 6] = ss;
        __syncthreads();
        const float tot = red[0] + red[1] + red[2] + red[3];
        const float rs = rsqrtf(tot * (1.0f / D_MODEL) + 1e-6f);
        const float4 wv = ((const float4*)ln1)[tid];
        u16* op = hb + (size_t)row * D_MODEL + tid * 4;
        u32 p0 = (u32)f2b(v.x * rs * wv.x) | ((u32)f2b(v.y * rs * wv.y) << 16);
        u32 p1 = (u32)f2b(v.z * rs * wv.z) | ((u32)f2b(v.w * rs * wv.w) << 16);
        uint2 pk; pk.x = p0; pk.y = p1;
        *(uint2*)op = pk;
        return;
    }

    // ---- transpose path ----
    const float* srcs[7] = {s0, s1, s2, s3, s4, s5, s6};
    u16* dsts[7] = {d0, d1, d2, d3, d4, d5, d6};
    const int RR[7] = {1024, 1024, 1024, 1024, 1024, 1024, 2730};
    const int CC[7] = {1024, 1024, 1024, 1024, 2730, 2730, 1024};
    const int OC[7] = {1024, 1024, 1024, 1024, 1024, 1024, 2880};
    const int XD[7] = {32, 32, 32, 32, 32, 32, 90};

    int seg, start;
    if (bid < 4096)      { seg = bid >> 10; start = seg << 10; }
    else if (bid < 6976) { seg = 4; start = 4096; }
    else if (bid < 9856) { seg = 5; start = 6976; }
    else                 { seg = 6; start = 9856; }
    const int local = bid - start;
    const int bx = local % XD[seg], byy = local / XD[seg];
    const float* in = srcs[seg];
    u16* out = dsts[seg];
    const int R = RR[seg], C = CC[seg], outC = OC[seg];

    const int r0 = byy * 32;
    const int c0 = bx * 32;
    const int tx = tid & 31, ty = tid >> 5;
#pragma unroll
    for (int j = 0; j < 4; ++j) {
        int ir = c0 + ty + j * 8;
        int ic = r0 + tx;
        t[ty + j * 8][tx] = (ir < R && ic < C) ? in[(size_t)ir * C + ic] : 0.0f;
    }
    __syncthreads();
#pragma unroll
    for (int j = 0; j < 4; ++j)
        out[(size_t)(r0 + ty + j * 8) * outC + c0 + tx] = f2b(t[tx][ty + j * 8]);
}

// ---------------------------------------------------------------------------
// RMSNorm (standalone, for x2 -> h2b)
// ---------------------------------------------------------------------------
__global__ __launch_bounds__(256)
void rmsnorm_k(const float* __restrict__ x, const float* __restrict__ w,
               u16* __restrict__ out) {
    const int row = blockIdx.x;
    const int tid = threadIdx.x;
    const float4 v = ((const float4*)(x + (size_t)row * D_MODEL))[tid];
    float ss = v.x * v.x + v.y * v.y + v.z * v.z + v.w * v.w;
    for (int o = 32; o; o >>= 1) ss += __shfl_down(ss, o);
    __shared__ float red[4];
    if ((tid & 63) == 0) red[tid >> 6] = ss;
    __syncthreads();
    const float tot = red[0] + red[1] + red[2] + red[3];
    const float rs = rsqrtf(tot * (1.0f / D_MODEL) + 1e-6f);
    const float4 wv = ((const float4*)w)[tid];
    u16* op = out + (size_t)row * D_MODEL + tid * 4;
    u32 p0 = (u32)f2b(v.x * rs * wv.x) | ((u32)f2b(v.y * rs * wv.y) << 16);
    u32 p1 = (u32)f2b(v.z * rs * wv.z) | ((u32)f2b(v.w * rs * wv.w) << 16);
    uint2 pk; pk.x = p0; pk.y = p1;
    *(uint2*)op = pk;
}

// ---------------------------------------------------------------------------
// Pack K/V per head, K-RoPE fused:
//   kp[h][s][d] = rope(qkv[s][1024 + h*64 + d])
//   vt[h][d][s] = qkv[s][2048 + h*64 + d]
// ---------------------------------------------------------------------------
__global__ __launch_bounds__(256)
void packkv_k(const u16* __restrict__ qkv, const float* __restrict__ fc,
              const float* __restrict__ fs, u16* __restrict__ vt,
              u16* __restrict__ kp) {
    __shared__ u16 t[32][33];
    const int h = blockIdx.z;
    const int t0 = blockIdx.x * 32;
    const int d0 = blockIdx.y * 32;
    const int tx = threadIdx.x, ty = threadIdx.y;
#pragma unroll
    for (int j = 0; j < 4; ++j)
        t[ty + j * 8][tx] =
            qkv[(size_t)(t0 + ty + j * 8) * QKV_LD + 2 * D_MODEL + h * DK + d0 + tx];

    const int id = ty * 32 + tx;
    const int sA = t0 + (id >> 3);
    const int dA = d0 + (id & 7) * 4;
    uint2 kvp = *(const uint2*)(qkv + (size_t)sA * QKV_LD + D_MODEL + h * DK + dA);
    const int fi = sA * 32 + (dA >> 1);
    const float cc0 = fc[fi], ss0 = fs[fi];
    const float cc1 = fc[fi + 1], ss1 = fs[fi + 1];
    auto rpk = [](u32 w, float c, float s) -> u32 {
        const float a = b2f((u16)w), b = b2f((u16)(w >> 16));
        return (u32)f2b(a * c - b * s) | ((u32)f2b(a * s + b * c) << 16);
    };
    kvp.x = rpk(kvp.x, cc0, ss0);
    kvp.y = rpk(kvp.y, cc1, ss1);
    *(uint2*)(kp + ((size_t)h * S_LEN + sA) * DK + dA) = kvp;

    __syncthreads();
#pragma unroll
    for (int j = 0; j < 4; ++j)
        vt[(size_t)h * DK * S_LEN + (size_t)(d0 + ty + j * 8) * S_LEN + t0 + tx] =
            t[tx][ty + j * 8];
}

// ---------------------------------------------------------------------------
// 128x128 GEMM (m97 structure): C = A @ Bt^T, global_load_lds staging.
// ---------------------------------------------------------------------------
template <int EPI>
__global__ __launch_bounds__(256)
void gemm128(const u16* __restrict__ A, int lda, const u16* __restrict__ Bt, int ldb,
             void* __restrict__ C, int ldc, int K, const float* __restrict__ resid) {
    const int m0 = blockIdx.y * 128, n0 = blockIdx.x * 128;
    const int tid = threadIdx.x;
    const int wave = tid >> 6, lane = tid & 63;
    const int wr = wave >> 1, wc = wave & 1;
    const int r16 = lane & 15, kq = lane >> 4;

    __shared__ __align__(16) u16 As[128 * 32];
    __shared__ __align__(16) u16 Bs[128 * 32];

    const int srow = tid >> 2, sk = (tid & 3) * 8;
    const u16* ag0 = A + (size_t)(m0 + srow) * lda + sk;
    const u16* ag1 = A + (size_t)(m0 + 64 + srow) * lda + sk;
    const u16* bg0 = Bt + (size_t)(n0 + srow) * ldb + sk;
    const u16* bg1 = Bt + (size_t)(n0 + 64 + srow) * ldb + sk;
    u16* asw = As + wave * 512;
    u16* bsw = Bs + wave * 512;

    f32x4 acc[16];
#pragma unroll
    for (int i = 0; i < 16; ++i) acc[i] = f32x4{0.f, 0.f, 0.f, 0.f};

    for (int k0 = 0; k0 < K; k0 += 32) {
        __syncthreads();
        gll16(ag0 + k0, asw);
        gll16(ag1 + k0, asw + 2048);
        gll16(bg0 + k0, bsw);
        gll16(bg1 + k0, bsw + 2048);
        __syncthreads();
        bf16x8 af[4], bf[4];
#pragma unroll
        for (int mt = 0; mt < 4; ++mt)
            af[mt] = *(const bf16x8*)&As[(wr * 64 + mt * 16 + r16) * 32 + kq * 8];
#pragma unroll
        for (int nt = 0; nt < 4; ++nt)
            bf[nt] = *(const bf16x8*)&Bs[(wc * 64 + nt * 16 + r16) * 32 + kq * 8];
#pragma unroll
        for (int mt = 0; mt < 4; ++mt)
#pragma unroll
            for (int nt = 0; nt < 4; ++nt)
                acc[mt * 4 + nt] = MFMA16(af[mt], bf[nt], acc[mt * 4 + nt], 0, 0, 0);
    }

#pragma unroll
    for (int mt = 0; mt < 4; ++mt) {
#pragma unroll
        for (int nt = 0; nt < 4; ++nt) {
            const int col = n0 + wc * 64 + nt * 16 + r16;
#pragma unroll
            for (int j = 0; j < 4; ++j) {
                const int row = m0 + wr * 64 + mt * 16 + kq * 4 + j;
                if (EPI == 0) {
                    ((u16*)C)[(size_t)row * ldc + col] = f2b(acc[mt * 4 + nt][j]);
                } else {
                    ((float*)C)[(size_t)row * ldc + col] =
                        resid[(size_t)row * ldc + col] + acc[mt * 4 + nt][j];
                }
            }
        }
    }
}

// ---------------------------------------------------------------------------
// 128(M) x 64(N) GEMM + fp32 residual epilogue (512 blocks at N=1024).
// ---------------------------------------------------------------------------
__global__ __launch_bounds__(256)
void gemm64r(const u16* __restrict__ A, int lda, const u16* __restrict__ Bt, int ldb,
             float* __restrict__ C, int ldc, int K, const float* __restrict__ resid) {
    const int m0 = blockIdx.y * 128, n0 = blockIdx.x * 64;
    const int tid = threadIdx.x;
    const int wave = tid >> 6, lane = tid & 63;
    const int r16 = lane & 15, kq = lane >> 4;

    __shared__ __align__(16) u16 As[128 * 32];
    __shared__ __align__(16) u16 Bs[64 * 32];

    const int srow = tid >> 2, sk = (tid & 3) * 8;
    const u16* ag0 = A + (size_t)(m0 + srow) * lda + sk;
    const u16* ag1 = A + (size_t)(m0 + 64 + srow) * lda + sk;
    const u16* bg = Bt + (size_t)(n0 + srow) * ldb + sk;
    u16* asw = As + wave * 512;
    u16* bsw = Bs + wave * 512;

    f32x4 acc[8];
#pragma unroll
    for (int i = 0; i < 8; ++i) acc[i] = f32x4{0.f, 0.f, 0.f, 0.f};

    for (int k0 = 0; k0 < K; k0 += 32) {
        __syncthreads();
        gll16(ag0 + k0, asw);
        gll16(ag1 + k0, asw + 2048);
        gll16(bg + k0, bsw);
        __syncthreads();
        bf16x8 af[2], bf[4];
#pragma unroll
        for (int mt = 0; mt < 2; ++mt)
            af[mt] = *(const bf16x8*)&As[(wave * 32 + mt * 16 + r16) * 32 + kq * 8];
#pragma unroll
        for (int nt = 0; nt < 4; ++nt)
            bf[nt] = *(const bf16x8*)&Bs[(nt * 16 + r16) * 32 + kq * 8];
#pragma unroll
        for (int mt = 0; mt < 2; ++mt)
#pragma unroll
            for (int nt = 0; nt < 4; ++nt)
                acc[mt * 4 + nt] = MFMA16(af[mt], bf[nt], acc[mt * 4 + nt], 0, 0, 0);
    }

#pragma unroll
    for (int mt = 0; mt < 2; ++mt)
#pragma unroll
        for (int nt = 0; nt < 4; ++nt) {
            const int col = n0 + nt * 16 + r16;
#pragma unroll
            for (int j = 0; j < 4; ++j) {
                const int row = m0 + wave * 32 + mt * 16 + kq * 4 + j;
                C[(size_t)row * ldc + col] =
                    resid[(size_t)row * ldc + col] + acc[mt * 4 + nt][j];
            }
        }
}

// ---------------------------------------------------------------------------
// FFN dual GEMM v3: tile 128(M) x 96(N per matrix), BK=64.
// Halves the per-K-step vmcnt(0)+barrier drains (the 2-phase critical path
// per m233: stage+drain+barrier ~72%).  BK=64 row stride (128B) would be a
// 16-way bank conflict, so staging uses pre-swizzled GLOBAL source columns
// (slot ^ (row&7)) with linear LDS dest (gll16 requirement) and the reads
// XOR the same pattern back -- same proven pattern as flash_k's K/V tiles.
// LDS = 16 + 24 = 40 KB; grid 960 = 3.75 blocks/CU (unchanged residency).
// ---------------------------------------------------------------------------
__global__ __launch_bounds__(256, 3)
void gemm_dual96x(const u16* __restrict__ A, int lda,
                  const u16* __restrict__ B1, const u16* __restrict__ B3, int ldb,
                  u16* __restrict__ C, int ldc, int K) {
    const int m0 = blockIdx.y * 128, n0 = blockIdx.x * 96;
    const int tid = threadIdx.x;
    const int wave = tid >> 6, lane = tid & 63;
    const int wr = wave >> 1, wc = wave & 1;
    const int r16 = lane & 15, kq = lane >> 4;

    __shared__ __align__(16) u16 As[128 * 64];   // swizzled rows
    __shared__ __align__(16) u16 Bs[192 * 64];   // rows 0-95 = B1, 96-191 = B3

    const int srow = tid >> 3;                       // 0..31 (row within call)
    const int scol = ((tid & 7) ^ (srow & 7)) * 8;   // pre-swizzled source col
    // 4 A-row-block pointers + 6 B-row-block pointers (32 rows per gll16 call)
    const u16* ag0 = A + (size_t)(m0 +  0 + srow) * lda + scol;
    const u16* ag1 = A + (size_t)(m0 + 32 + srow) * lda + scol;
    const u16* ag2 = A + (size_t)(m0 + 64 + srow) * lda + scol;
    const u16* ag3 = A + (size_t)(m0 + 96 + srow) * lda + scol;
    const u16* bg0 = B1 + (size_t)(n0 +  0 + srow) * ldb + scol;
    const u16* bg1 = B1 + (size_t)(n0 + 32 + srow) * ldb + scol;
    const u16* bg2 = B1 + (size_t)(n0 + 64 + srow) * ldb + scol;
    const u16* bg3 = B3 + (size_t)(n0 +  0 + srow) * ldb + scol;
    const u16* bg4 = B3 + (size_t)(n0 + 32 + srow) * ldb + scol;
    const u16* bg5 = B3 + (size_t)(n0 + 64 + srow) * ldb + scol;
    u16* const ad = As + tid * 8;
    u16* const bd = Bs + tid * 8;

    f32x4 acc1[12], acc3[12];
#pragma unroll
    for (int i = 0; i < 12; ++i) {
        acc1[i] = f32x4{0.f, 0.f, 0.f, 0.f};
        acc3[i] = f32x4{0.f, 0.f, 0.f, 0.f};
    }

    const int rsw = r16 & 7;
    for (int k0 = 0; k0 < K; k0 += 64) {
        __syncthreads();
        gll16(ag0 + k0, ad);
        gll16(ag1 + k0, ad + 2048);
        gll16(ag2 + k0, ad + 4096);
        gll16(ag3 + k0, ad + 6144);
        gll16(bg0 + k0, bd);
        gll16(bg1 + k0, bd + 2048);
        gll16(bg2 + k0, bd + 4096);
        gll16(bg3 + k0, bd + 6144);
        gll16(bg4 + k0, bd + 8192);
        gll16(bg5 + k0, bd + 10240);
        __syncthreads();
#pragma unroll
        for (int ks = 0; ks < 2; ++ks) {
            const int slot = (((ks << 2) | kq) ^ rsw) * 8;
            bf16x8 af[4], b1f[3], b3f[3];
#pragma unroll
            for (int mt = 0; mt < 4; ++mt)
                af[mt] = *(const bf16x8*)&As[(wr * 64 + mt * 16 + r16) * 64 + slot];
#pragma unroll
            for (int nt = 0; nt < 3; ++nt) {
                b1f[nt] = *(const bf16x8*)&Bs[(wc * 48 + nt * 16 + r16) * 64 + slot];
                b3f[nt] = *(const bf16x8*)&Bs[(96 + wc * 48 + nt * 16 + r16) * 64 + slot];
            }
#pragma unroll
            for (int mt = 0; mt < 4; ++mt)
#pragma unroll
                for (int nt = 0; nt < 3; ++nt) {
                    acc1[mt * 3 + nt] = MFMA16(af[mt], b1f[nt], acc1[mt * 3 + nt], 0, 0, 0);
                    acc3[mt * 3 + nt] = MFMA16(af[mt], b3f[nt], acc3[mt * 3 + nt], 0, 0, 0);
                }
        }
    }

#pragma unroll
    for (int mt = 0; mt < 4; ++mt)
#pragma unroll
        for (int nt = 0; nt < 3; ++nt) {
            const int col = n0 + wc * 48 + nt * 16 + r16;
#pragma unroll
            for (int j = 0; j < 4; ++j) {
                const int row = m0 + wr * 64 + mt * 16 + kq * 4 + j;
                const float v1 = acc1[mt * 3 + nt][j];
                const float v3 = acc3[mt * 3 + nt][j];
                const float sig = 1.0f / (1.0f + __expf(-v1));
                C[(size_t)row * ldc + col] = f2b(v1 * sig * v3);
            }
        }
}

// ---------------------------------------------------------------------------
// Flash attention v8: interleaved causal pairing, sync structure UNCHANGED
// from the verified v6 kernel. Block (h, pair) handles q-tiles qa=pair and
// qb=63-pair in ONE kv sweep t=0..qb: per tile, compute the qb part always
// and the qa part while t<=qa -> uniform 65 tile-computes per block.
// Grid 512 = 2 blocks/CU, no occupancy-decay tail (was: 1..64-tile blocks at
// exactly-capacity grid). Same single barrier + prefetch-after-barrier per
// tile; only register-level additions (2nd Q, o, lacc; wave-uniform branch).
// LDS = 2*(8+8) + 8 = 40 KB.
// ---------------------------------------------------------------------------
__global__ __launch_bounds__(256)
void flash_k(const u16* __restrict__ qkv, const u16* __restrict__ vt,
             const u16* __restrict__ kp, const float* __restrict__ fc,
             const float* __restrict__ fs, u16* __restrict__ ctx) {
    const int h = blockIdx.x;
    const int pair = blockIdx.y;       // 0..31
    const int qa = pair, qb = 63 - pair;
    const int tid = threadIdx.x;
    const int wave = tid >> 6, lane = tid & 63;
    const int r16 = lane & 15, kq = lane >> 4;

    __shared__ __align__(16) u16 Kb[2][64 * 64];   // XOR-chunk-swizzled
    __shared__ __align__(16) u16 Vb[2][64 * 64];
    __shared__ __align__(16) u16 Ps[4 * 16 * 64];  // per-wave [q][kv], swizzled

    const u16* kb = kp + (size_t)h * S_LEN * DK;
    const u16* vb = vt + (size_t)h * DK * S_LEN;
    const int srow = tid >> 3;
    const int lcol = ((tid & 7) ^ (srow & 7)) * 8;
    const int qloc = wave * 16 + r16;
    const int sw = r16 & 7;
    const int c0 = (kq ^ sw) * 8;
    const int c1 = ((4 ^ kq) ^ sw) * 8;
    const int psw = r16 & 14;
    u16* psrow = Ps + wave * 1024 + r16 * 64;

    const float SC = 0.125f * 1.44269504f;
    auto rp = [SC](u32 w, float c, float s) -> u32 {
        const float a = b2f((u16)w), b = b2f((u16)(w >> 16));
        return (u32)f2b((a * c - b * s) * SC) |
               ((u32)f2b((a * s + b * c) * SC) << 16);
    };
    // Q: raw load + RoPE + scale, in registers (for both q-tiles)
    auto loadq = [&](int qglob, bf16x8& q0out, bf16x8& q1out) {
        const u16* qrow = qkv + (size_t)qglob * QKV_LD + h * DK;
        uint4 uq0 = *(const uint4*)(qrow + kq * 8);
        uint4 uq1 = *(const uint4*)(qrow + 32 + kq * 8);
        const float4 c0v = *(const float4*)(fc + qglob * 32 + kq * 4);
        const float4 s0v = *(const float4*)(fs + qglob * 32 + kq * 4);
        const float4 c1v = *(const float4*)(fc + qglob * 32 + 16 + kq * 4);
        const float4 s1v = *(const float4*)(fs + qglob * 32 + 16 + kq * 4);
        uq0.x = rp(uq0.x, c0v.x, s0v.x); uq0.y = rp(uq0.y, c0v.y, s0v.y);
        uq0.z = rp(uq0.z, c0v.z, s0v.z); uq0.w = rp(uq0.w, c0v.w, s0v.w);
        uq1.x = rp(uq1.x, c1v.x, s1v.x); uq1.y = rp(uq1.y, c1v.y, s1v.y);
        uq1.z = rp(uq1.z, c1v.z, s1v.z); uq1.w = rp(uq1.w, c1v.w, s1v.w);
        q0out = __builtin_bit_cast(bf16x8, uq0);
        q1out = __builtin_bit_cast(bf16x8, uq1);
    };
    const int qgA = qa * 64 + qloc;
    const int qgB = qb * 64 + qloc;
    bf16x8 qfA0, qfA1, qfB0, qfB1;
    loadq(qgA, qfA0, qfA1);
    loadq(qgB, qfB0, qfB1);

    f32x4 oA[4], oB[4];
#pragma unroll
    for (int i = 0; i < 4; ++i) {
        oA[i] = f32x4{0.f, 0.f, 0.f, 0.f};
        oB[i] = f32x4{0.f, 0.f, 0.f, 0.f};
    }
    f32x4 laccA = f32x4{0.f, 0.f, 0.f, 0.f};
    f32x4 laccB = f32x4{0.f, 0.f, 0.f, 0.f};
    const uint4 uone = make_uint4(0x3F803F80u, 0x3F803F80u, 0x3F803F80u, 0x3F803F80u);
    const bf16x8 ones = __builtin_bit_cast(bf16x8, uone);

    // per-tile compute: S^T = K.Q^T -> p=2^s (diag-masked on last tile) ->
    // packed P^T via swizzled wave-private Ps -> O^T += V^T@P^T, l += 1@P^T
    auto tilec = [&](const u16* Ks, const u16* Vs, const bf16x8& q0f,
                     const bf16x8& q1f, f32x4 (&o)[4], f32x4& lacc, bool dmask) {
        f32x4 s[4];
#pragma unroll
        for (int nt = 0; nt < 4; ++nt) {
            s[nt] = f32x4{0.f, 0.f, 0.f, 0.f};
            const bf16x8 k0 = *(const bf16x8*)&Ks[(nt * 16 + r16) * 64 + c0];
            s[nt] = MFMA16(k0, q0f, s[nt], 0, 0, 0);
            const bf16x8 k1 = *(const bf16x8*)&Ks[(nt * 16 + r16) * 64 + c1];
            s[nt] = MFMA16(k1, q1f, s[nt], 0, 0, 0);
        }
        float pr[16];
#pragma unroll
        for (int nt = 0; nt < 4; ++nt)
#pragma unroll
            for (int j = 0; j < 4; ++j) pr[nt * 4 + j] = EXP2(s[nt][j]);
        if (dmask) {
#pragma unroll
            for (int nt = 0; nt < 4; ++nt)
#pragma unroll
                for (int j = 0; j < 4; ++j)
                    if ((nt * 16 + kq * 4 + j) > qloc) pr[nt * 4 + j] = 0.f;
        }
#pragma unroll
        for (int nt = 0; nt < 4; ++nt) {
            uint2 pk;
            pk.x = pk_trunc(pr[nt * 4 + 0], pr[nt * 4 + 1]);
            pk.y = pk_trunc(pr[nt * 4 + 2], pr[nt * 4 + 3]);
            *(uint2*)&psrow[((nt * 4 + kq) ^ psw) * 4] = pk;
        }
#pragma unroll
        for (int ks = 0; ks < 2; ++ks) {
            const bf16x8 pf = *(const bf16x8*)&psrow[((8 * ks + 2 * kq) ^ psw) * 4];
            lacc = MFMA16(ones, pf, lacc, 0, 0, 0);
            const int cv = (((ks << 2) ^ kq) ^ sw) * 8;
#pragma unroll
            for (int nt = 0; nt < 4; ++nt) {
                const bf16x8 vf = *(const bf16x8*)&Vs[(nt * 16 + r16) * 64 + cv];
                o[nt] = MFMA16(vf, pf, o[nt], 0, 0, 0);
            }
        }
    };

    // preload tile 0 into buffer 0
#pragma unroll
    for (int i = 0; i < 2; ++i) {
        const int r = srow + i * 32;
        gll16(kb + (size_t)r * DK + lcol, Kb[0] + tid * 8 + i * 2048);
        gll16(vb + (size_t)r * S_LEN + lcol, Vb[0] + tid * 8 + i * 2048);
    }

    for (int t = 0; t <= qb; ++t) {
        __syncthreads();   // drains tile-t loads; all waves done with buf[(t+1)&1]
        if (t < qb) {      // issue next-tile loads NOW; they overlap compute below
            const int t1 = (t + 1) * 64;
            u16* kd = Kb[(t + 1) & 1];
            u16* vd = Vb[(t + 1) & 1];
#pragma unroll
            for (int i = 0; i < 2; ++i) {
                const int r = srow + i * 32;
                gll16(kb + (size_t)(t1 + r) * DK + lcol, kd + tid * 8 + i * 2048);
                gll16(vb + (size_t)r * S_LEN + t1 + lcol, vd + tid * 8 + i * 2048);
            }
        }
        const u16* Ks = Kb[t & 1];
        const u16* Vs = Vb[t & 1];

        tilec(Ks, Vs, qfB0, qfB1, oB, laccB, t == qb);
        if (t <= qa)
            tilec(Ks, Vs, qfA0, qfA1, oA, laccA, t == qa);
    }

    // l: every lacc element equals the full sum for column q=r16
    auto wout = [&](f32x4 (&o)[4], float lsum, int qg) {
        const float inv = 1.0f / lsum;
        const size_t row = qg;
#pragma unroll
        for (int nt = 0; nt < 4; ++nt) {
            uint2 pk;
            pk.x = (u32)f2b(o[nt][0] * inv) | ((u32)f2b(o[nt][1] * inv) << 16);
            pk.y = (u32)f2b(o[nt][2] * inv) | ((u32)f2b(o[nt][3] * inv) << 16);
            *(uint2*)&ctx[row * D_MODEL + h * DK + nt * 16 + kq * 4] = pk;
        }
    };
    wout(oA, laccA[0], qgA);
    wout(oB, laccB[0], qgB);
}

// ---------------------------------------------------------------------------
extern "C" void kernel_launch(void* const* d_in, const int* in_sizes, int n_in,
                              void* d_out, int out_size, void* d_ws, size_t ws_size,
                              hipStream_t stream) {
    const float* x    = (const float*)d_in[0];
    const float* fcos = (const float*)d_in[1];
    const float* fsin = (const float*)d_in[2];
    const float* Wq = (const float*)d_in[4];
    const float* Wk = (const float*)d_in[5];
    const float* Wv = (const float*)d_in[6];
    const float* Wo = (const float*)d_in[7];
    const float* ln1 = (const float*)d_in[8];
    const float* ln2 = (const float*)d_in[9];
    const float* w1 = (const float*)d_in[10];
    const float* w2 = (const float*)d_in[11];
    const float* w3 = (const float*)d_in[12];
    float* out = (float*)d_out;

    char* ws = (char*)d_ws;
    size_t off = 0;
    auto alloc = [&](size_t bytes) -> char* {
        char* p = ws + off;
        off += (bytes + 255) & ~(size_t)255;
        return p;
    };
    u16* hb    = (u16*)alloc((size_t)S_LEN * D_MODEL * 2);
    u16* wqkvt = (u16*)alloc((size_t)QKV_LD * D_MODEL * 2);  // [3072][1024]
    u16* wot   = (u16*)alloc((size_t)D_MODEL * D_MODEL * 2);
    u16* qkvb  = (u16*)alloc((size_t)S_LEN * QKV_LD * 2);    // [4096][3072]
    u16* vt    = (u16*)alloc((size_t)S_LEN * D_MODEL * 2);   // [H][DK][S]
    u16* kpack = (u16*)alloc((size_t)S_LEN * D_MODEL * 2);   // [H][S][DK]
    u16* ctxb  = (u16*)alloc((size_t)S_LEN * D_MODEL * 2);
    float* x2  = (float*)alloc((size_t)S_LEN * D_MODEL * 4);
    u16* h2b   = (u16*)alloc((size_t)S_LEN * D_MODEL * 2);
    u16* w1t   = (u16*)alloc((size_t)HIDP * D_MODEL * 2);    // [2880][1024]
    u16* w3t   = (u16*)alloc((size_t)HIDP * D_MODEL * 2);
    u16* w2t   = (u16*)alloc((size_t)D_MODEL * HIDP * 2);    // [1024][2880]
    u16* ffb   = (u16*)alloc((size_t)S_LEN * HIDP * 2);      // [4096][2880]

    const dim3 tb32(32, 8);

    // weight transposes + rmsnorm(x, ln1), one launch
    prep_k<<<16832, 256, 0, stream>>>(
        Wq, Wk, Wv, Wo, w1, w3, w2,
        wqkvt, wqkvt + (size_t)D_MODEL * D_MODEL,
        wqkvt + (size_t)2 * D_MODEL * D_MODEL, wot, w1t, w3t, w2t,
        x, ln1, hb);

    // QKV = h @ [Wq|Wk|Wv]   (one 4096x3072x1024 GEMM, raw Q/K)
    gemm128<0><<<dim3(QKV_LD / 128, S_LEN / 128), 256, 0, stream>>>(
        hb, D_MODEL, wqkvt, D_MODEL, qkvb, QKV_LD, D_MODEL, nullptr);

    // K packed (+RoPE) + V transposed per head
    packkv_k<<<dim3(S_LEN / 32, DK / 32, NHEAD), tb32, 0, stream>>>(
        qkvb, fcos, fsin, vt, kpack);

    // flash attention (Q RoPE fused; interleaved causal pairing, 512 blocks)
    flash_k<<<dim3(NHEAD, 32), 256, 0, stream>>>(qkvb, vt, kpack, fcos, fsin, ctxb);

    // x2 = x + ctx @ Wo
    gemm64r<<<dim3(D_MODEL / 64, S_LEN / 128), 256, 0, stream>>>(
        ctxb, D_MODEL, wot, D_MODEL, x2, D_MODEL, D_MODEL, x);

    // h2 = rmsnorm(x2, ln2)
    rmsnorm_k<<<S_LEN, 256, 0, stream>>>(x2, ln2, h2b);

    // ff = silu(h2@w1) * (h2@w3)
    gemm_dual96x<<<dim3(HIDP / 96, S_LEN / 128), 256, 0, stream>>>(
        h2b, D_MODEL, w1t, w3t, D_MODEL, ffb, HIDP, D_MODEL);

    // out = x2 + ff @ w2
    gemm64r<<<dim3(D_MODEL / 64, S_LEN / 128), 256, 0, stream>>>(
        ffb, HIDP, w2t, HIDP, out, D_MODEL, HIDP, x2);
}

// Round 5
// 426.073 us; speedup vs baseline: 1.0030x; 1.0030x over previous
//
#include <hip/hip_runtime.h>

#define S_LEN 4096
#define D_MODEL 1024
#define NHEAD 16
#define DK 64
#define HID 2730
#define HIDP 2880
#define QKV_LD 3072

typedef unsigned short u16;
typedef unsigned int u32;
typedef __bf16 bf16x8 __attribute__((ext_vector_type(8)));
typedef float f32x4 __attribute__((ext_vector_type(4)));

#define MFMA16 __builtin_amdgcn_mfma_f32_16x16x32_bf16
// raw v_exp_f32 (2^x): scores bounded (|s| < ~30), no OCML guard code needed
#define EXP2 __builtin_amdgcn_exp2f

__device__ __forceinline__ float b2f(u16 u) {
    return __builtin_bit_cast(float, (u32)u << 16);
}
__device__ __forceinline__ u16 f2b(float f) {
    u32 u = __builtin_bit_cast(u32, f);
    u += 0x7FFF + ((u >> 16) & 1);
    return (u16)(u >> 16);
}
// pack two f32 -> two bf16 (truncate) in one v_perm_b32
__device__ __forceinline__ u32 pk_trunc(float lo, float hi) {
    return __builtin_amdgcn_perm(__builtin_bit_cast(u32, hi),
                                 __builtin_bit_cast(u32, lo), 0x07060302u);
}
// async global->LDS, 16B per lane; dest must be wave-uniform base + lane*16
__device__ __forceinline__ void gll16(const u16* g, u16* l) {
    __builtin_amdgcn_global_load_lds(
        (__attribute__((address_space(1))) void*)(g),
        (__attribute__((address_space(3))) void*)(l),
        16, 0, 0);
}

// ---------------------------------------------------------------------------
// Prep: 7 weight transposes (fp32->bf16, zero-pad) + rmsnorm(x, ln1) in ONE
// launch. Flat grid, 256-thread blocks. Blocks 0..12735 = tcast segments;
// blocks 12736..16831 = rmsnorm rows.  (HIDP = 2880 = 30*96)
// ---------------------------------------------------------------------------
__global__ __launch_bounds__(256)
void prep_k(const float* s0, const float* s1, const float* s2,
            const float* s3, const float* s4, const float* s5,
            const float* s6, u16* d0, u16* d1, u16* d2, u16* d3,
            u16* d4, u16* d5, u16* d6,
            const float* __restrict__ x, const float* __restrict__ ln1,
            u16* __restrict__ hb) {
    __shared__ float t[32][33];
    __shared__ float red[4];
    const int bid = blockIdx.x;
    const int tid = threadIdx.x;

    if (bid >= 12736) {   // ---- rmsnorm path ----
        const int row = bid - 12736;
        const float4 v = ((const float4*)(x + (size_t)row * D_MODEL))[tid];
        float ss = v.x * v.x + v.y * v.y + v.z * v.z + v.w * v.w;
        for (int o = 32; o; o >>= 1) ss += __shfl_down(ss, o);
        if ((tid & 63) == 0) red[tid >> 6] = ss;
        __syncthreads();
        const float tot = red[0] + red[1] + red[2] + red[3];
        const float rs = rsqrtf(tot * (1.0f / D_MODEL) + 1e-6f);
        const float4 wv = ((const float4*)ln1)[tid];
        u16* op = hb + (size_t)row * D_MODEL + tid * 4;
        u32 p0 = (u32)f2b(v.x * rs * wv.x) | ((u32)f2b(v.y * rs * wv.y) << 16);
        u32 p1 = (u32)f2b(v.z * rs * wv.z) | ((u32)f2b(v.w * rs * wv.w) << 16);
        uint2 pk; pk.x = p0; pk.y = p1;
        *(uint2*)op = pk;
        return;
    }

    // ---- transpose path ----
    const float* srcs[7] = {s0, s1, s2, s3, s4, s5, s6};
    u16* dsts[7] = {d0, d1, d2, d3, d4, d5, d6};
    const int RR[7] = {1024, 1024, 1024, 1024, 1024, 1024, 2730};
    const int CC[7] = {1024, 1024, 1024, 1024, 2730, 2730, 1024};
    const int OC[7] = {1024, 1024, 1024, 1024, 1024, 1024, 2880};
    const int XD[7] = {32, 32, 32, 32, 32, 32, 90};

    int seg, start;
    if (bid < 4096)      { seg = bid >> 10; start = seg << 10; }
    else if (bid < 6976) { seg = 4; start = 4096; }
    else if (bid < 9856) { seg = 5; start = 6976; }
    else                 { seg = 6; start = 9856; }
    const int local = bid - start;
    const int bx = local % XD[seg], byy = local / XD[seg];
    const float* in = srcs[seg];
    u16* out = dsts[seg];
    const int R = RR[seg], C = CC[seg], outC = OC[seg];

    const int r0 = byy * 32;
    const int c0 = bx * 32;
    const int tx = tid & 31, ty = tid >> 5;
#pragma unroll
    for (int j = 0; j < 4; ++j) {
        int ir = c0 + ty + j * 8;
        int ic = r0 + tx;
        t[ty + j * 8][tx] = (ir < R && ic < C) ? in[(size_t)ir * C + ic] : 0.0f;
    }
    __syncthreads();
#pragma unroll
    for (int j = 0; j < 4; ++j)
        out[(size_t)(r0 + ty + j * 8) * outC + c0 + tx] = f2b(t[tx][ty + j * 8]);
}

// ---------------------------------------------------------------------------
// RMSNorm (standalone, for x2 -> h2b)
// ---------------------------------------------------------------------------
__global__ __launch_bounds__(256)
void rmsnorm_k(const float* __restrict__ x, const float* __restrict__ w,
               u16* __restrict__ out) {
    const int row = blockIdx.x;
    const int tid = threadIdx.x;
    const float4 v = ((const float4*)(x + (size_t)row * D_MODEL))[tid];
    float ss = v.x * v.x + v.y * v.y + v.z * v.z + v.w * v.w;
    for (int o = 32; o; o >>= 1) ss += __shfl_down(ss, o);
    __shared__ float red[4];
    if ((tid & 63) == 0) red[tid >> 6] = ss;
    __syncthreads();
    const float tot = red[0] + red[1] + red[2] + red[3];
    const float rs = rsqrtf(tot * (1.0f / D_MODEL) + 1e-6f);
    const float4 wv = ((const float4*)w)[tid];
    u16* op = out + (size_t)row * D_MODEL + tid * 4;
    u32 p0 = (u32)f2b(v.x * rs * wv.x) | ((u32)f2b(v.y * rs * wv.y) << 16);
    u32 p1 = (u32)f2b(v.z * rs * wv.z) | ((u32)f2b(v.w * rs * wv.w) << 16);
    uint2 pk; pk.x = p0; pk.y = p1;
    *(uint2*)op = pk;
}

// ---------------------------------------------------------------------------
// Pack K/V per head, K-RoPE fused:
//   kp[h][s][d] = rope(qkv[s][1024 + h*64 + d])
//   vt[h][d][s] = qkv[s][2048 + h*64 + d]
// ---------------------------------------------------------------------------
__global__ __launch_bounds__(256)
void packkv_k(const u16* __restrict__ qkv, const float* __restrict__ fc,
              const float* __restrict__ fs, u16* __restrict__ vt,
              u16* __restrict__ kp) {
    __shared__ u16 t[32][33];
    const int h = blockIdx.z;
    const int t0 = blockIdx.x * 32;
    const int d0 = blockIdx.y * 32;
    const int tx = threadIdx.x, ty = threadIdx.y;
#pragma unroll
    for (int j = 0; j < 4; ++j)
        t[ty + j * 8][tx] =
            qkv[(size_t)(t0 + ty + j * 8) * QKV_LD + 2 * D_MODEL + h * DK + d0 + tx];

    const int id = ty * 32 + tx;
    const int sA = t0 + (id >> 3);
    const int dA = d0 + (id & 7) * 4;
    uint2 kvp = *(const uint2*)(qkv + (size_t)sA * QKV_LD + D_MODEL + h * DK + dA);
    const int fi = sA * 32 + (dA >> 1);
    const float cc0 = fc[fi], ss0 = fs[fi];
    const float cc1 = fc[fi + 1], ss1 = fs[fi + 1];
    auto rpk = [](u32 w, float c, float s) -> u32 {
        const float a = b2f((u16)w), b = b2f((u16)(w >> 16));
        return (u32)f2b(a * c - b * s) | ((u32)f2b(a * s + b * c) << 16);
    };
    kvp.x = rpk(kvp.x, cc0, ss0);
    kvp.y = rpk(kvp.y, cc1, ss1);
    *(uint2*)(kp + ((size_t)h * S_LEN + sA) * DK + dA) = kvp;

    __syncthreads();
#pragma unroll
    for (int j = 0; j < 4; ++j)
        vt[(size_t)h * DK * S_LEN + (size_t)(d0 + ty + j * 8) * S_LEN + t0 + tx] =
            t[tx][ty + j * 8];
}

// ---------------------------------------------------------------------------
// 128x128 GEMM (m97 structure): C = A @ Bt^T, global_load_lds staging.
// ---------------------------------------------------------------------------
template <int EPI>
__global__ __launch_bounds__(256)
void gemm128(const u16* __restrict__ A, int lda, const u16* __restrict__ Bt, int ldb,
             void* __restrict__ C, int ldc, int K, const float* __restrict__ resid) {
    const int m0 = blockIdx.y * 128, n0 = blockIdx.x * 128;
    const int tid = threadIdx.x;
    const int wave = tid >> 6, lane = tid & 63;
    const int wr = wave >> 1, wc = wave & 1;
    const int r16 = lane & 15, kq = lane >> 4;

    __shared__ __align__(16) u16 As[128 * 32];
    __shared__ __align__(16) u16 Bs[128 * 32];

    const int srow = tid >> 2, sk = (tid & 3) * 8;
    const u16* ag0 = A + (size_t)(m0 + srow) * lda + sk;
    const u16* ag1 = A + (size_t)(m0 + 64 + srow) * lda + sk;
    const u16* bg0 = Bt + (size_t)(n0 + srow) * ldb + sk;
    const u16* bg1 = Bt + (size_t)(n0 + 64 + srow) * ldb + sk;
    u16* asw = As + wave * 512;
    u16* bsw = Bs + wave * 512;

    f32x4 acc[16];
#pragma unroll
    for (int i = 0; i < 16; ++i) acc[i] = f32x4{0.f, 0.f, 0.f, 0.f};

    for (int k0 = 0; k0 < K; k0 += 32) {
        __syncthreads();
        gll16(ag0 + k0, asw);
        gll16(ag1 + k0, asw + 2048);
        gll16(bg0 + k0, bsw);
        gll16(bg1 + k0, bsw + 2048);
        __syncthreads();
        bf16x8 af[4], bf[4];
#pragma unroll
        for (int mt = 0; mt < 4; ++mt)
            af[mt] = *(const bf16x8*)&As[(wr * 64 + mt * 16 + r16) * 32 + kq * 8];
#pragma unroll
        for (int nt = 0; nt < 4; ++nt)
            bf[nt] = *(const bf16x8*)&Bs[(wc * 64 + nt * 16 + r16) * 32 + kq * 8];
#pragma unroll
        for (int mt = 0; mt < 4; ++mt)
#pragma unroll
            for (int nt = 0; nt < 4; ++nt)
                acc[mt * 4 + nt] = MFMA16(af[mt], bf[nt], acc[mt * 4 + nt], 0, 0, 0);
    }

#pragma unroll
    for (int mt = 0; mt < 4; ++mt) {
#pragma unroll
        for (int nt = 0; nt < 4; ++nt) {
            const int col = n0 + wc * 64 + nt * 16 + r16;
#pragma unroll
            for (int j = 0; j < 4; ++j) {
                const int row = m0 + wr * 64 + mt * 16 + kq * 4 + j;
                if (EPI == 0) {
                    ((u16*)C)[(size_t)row * ldc + col] = f2b(acc[mt * 4 + nt][j]);
                } else {
                    ((float*)C)[(size_t)row * ldc + col] =
                        resid[(size_t)row * ldc + col] + acc[mt * 4 + nt][j];
                }
            }
        }
    }
}

// ---------------------------------------------------------------------------
// 128(M) x 64(N) GEMM + fp32 residual epilogue (512 blocks at N=1024).
// ---------------------------------------------------------------------------
__global__ __launch_bounds__(256)
void gemm64r(const u16* __restrict__ A, int lda, const u16* __restrict__ Bt, int ldb,
             float* __restrict__ C, int ldc, int K, const float* __restrict__ resid) {
    const int m0 = blockIdx.y * 128, n0 = blockIdx.x * 64;
    const int tid = threadIdx.x;
    const int wave = tid >> 6, lane = tid & 63;
    const int r16 = lane & 15, kq = lane >> 4;

    __shared__ __align__(16) u16 As[128 * 32];
    __shared__ __align__(16) u16 Bs[64 * 32];

    const int srow = tid >> 2, sk = (tid & 3) * 8;
    const u16* ag0 = A + (size_t)(m0 + srow) * lda + sk;
    const u16* ag1 = A + (size_t)(m0 + 64 + srow) * lda + sk;
    const u16* bg = Bt + (size_t)(n0 + srow) * ldb + sk;
    u16* asw = As + wave * 512;
    u16* bsw = Bs + wave * 512;

    f32x4 acc[8];
#pragma unroll
    for (int i = 0; i < 8; ++i) acc[i] = f32x4{0.f, 0.f, 0.f, 0.f};

    for (int k0 = 0; k0 < K; k0 += 32) {
        __syncthreads();
        gll16(ag0 + k0, asw);
        gll16(ag1 + k0, asw + 2048);
        gll16(bg + k0, bsw);
        __syncthreads();
        bf16x8 af[2], bf[4];
#pragma unroll
        for (int mt = 0; mt < 2; ++mt)
            af[mt] = *(const bf16x8*)&As[(wave * 32 + mt * 16 + r16) * 32 + kq * 8];
#pragma unroll
        for (int nt = 0; nt < 4; ++nt)
            bf[nt] = *(const bf16x8*)&Bs[(nt * 16 + r16) * 32 + kq * 8];
#pragma unroll
        for (int mt = 0; mt < 2; ++mt)
#pragma unroll
            for (int nt = 0; nt < 4; ++nt)
                acc[mt * 4 + nt] = MFMA16(af[mt], bf[nt], acc[mt * 4 + nt], 0, 0, 0);
    }

#pragma unroll
    for (int mt = 0; mt < 2; ++mt)
#pragma unroll
        for (int nt = 0; nt < 4; ++nt) {
            const int col = n0 + nt * 16 + r16;
#pragma unroll
            for (int j = 0; j < 4; ++j) {
                const int row = m0 + wave * 32 + mt * 16 + kq * 4 + j;
                C[(size_t)row * ldc + col] =
                    resid[(size_t)row * ldc + col] + acc[mt * 4 + nt][j];
            }
        }
}

// ---------------------------------------------------------------------------
// FFN dual GEMM v3: tile 128(M) x 96(N per matrix), BK=64.
// Halves the per-K-step vmcnt(0)+barrier drains (the 2-phase critical path
// per m233: stage+drain+barrier ~72%).  BK=64 row stride (128B) would be a
// 16-way bank conflict, so staging uses pre-swizzled GLOBAL source columns
// (slot ^ (row&7)) with linear LDS dest (gll16 requirement) and the reads
// XOR the same pattern back -- same proven pattern as flash_k's K/V tiles.
// LDS = 16 + 24 = 40 KB; grid 960 = 3.75 blocks/CU (unchanged residency).
// ---------------------------------------------------------------------------
__global__ __launch_bounds__(256, 3)
void gemm_dual96x(const u16* __restrict__ A, int lda,
                  const u16* __restrict__ B1, const u16* __restrict__ B3, int ldb,
                  u16* __restrict__ C, int ldc, int K) {
    const int m0 = blockIdx.y * 128, n0 = blockIdx.x * 96;
    const int tid = threadIdx.x;
    const int wave = tid >> 6, lane = tid & 63;
    const int wr = wave >> 1, wc = wave & 1;
    const int r16 = lane & 15, kq = lane >> 4;

    __shared__ __align__(16) u16 As[128 * 64];   // swizzled rows
    __shared__ __align__(16) u16 Bs[192 * 64];   // rows 0-95 = B1, 96-191 = B3

    const int srow = tid >> 3;                       // 0..31 (row within call)
    const int scol = ((tid & 7) ^ (srow & 7)) * 8;   // pre-swizzled source col
    // 4 A-row-block pointers + 6 B-row-block pointers (32 rows per gll16 call)
    const u16* ag0 = A + (size_t)(m0 +  0 + srow) * lda + scol;
    const u16* ag1 = A + (size_t)(m0 + 32 + srow) * lda + scol;
    const u16* ag2 = A + (size_t)(m0 + 64 + srow) * lda + scol;
    const u16* ag3 = A + (size_t)(m0 + 96 + srow) * lda + scol;
    const u16* bg0 = B1 + (size_t)(n0 +  0 + srow) * ldb + scol;
    const u16* bg1 = B1 + (size_t)(n0 + 32 + srow) * ldb + scol;
    const u16* bg2 = B1 + (size_t)(n0 + 64 + srow) * ldb + scol;
    const u16* bg3 = B3 + (size_t)(n0 +  0 + srow) * ldb + scol;
    const u16* bg4 = B3 + (size_t)(n0 + 32 + srow) * ldb + scol;
    const u16* bg5 = B3 + (size_t)(n0 + 64 + srow) * ldb + scol;
    u16* const ad = As + tid * 8;
    u16* const bd = Bs + tid * 8;

    f32x4 acc1[12], acc3[12];
#pragma unroll
    for (int i = 0; i < 12; ++i) {
        acc1[i] = f32x4{0.f, 0.f, 0.f, 0.f};
        acc3[i] = f32x4{0.f, 0.f, 0.f, 0.f};
    }

    const int rsw = r16 & 7;
    for (int k0 = 0; k0 < K; k0 += 64) {
        __syncthreads();
        gll16(ag0 + k0, ad);
        gll16(ag1 + k0, ad + 2048);
        gll16(ag2 + k0, ad + 4096);
        gll16(ag3 + k0, ad + 6144);
        gll16(bg0 + k0, bd);
        gll16(bg1 + k0, bd + 2048);
        gll16(bg2 + k0, bd + 4096);
        gll16(bg3 + k0, bd + 6144);
        gll16(bg4 + k0, bd + 8192);
        gll16(bg5 + k0, bd + 10240);
        __syncthreads();
#pragma unroll
        for (int ks = 0; ks < 2; ++ks) {
            const int slot = (((ks << 2) | kq) ^ rsw) * 8;
            bf16x8 af[4], b1f[3], b3f[3];
#pragma unroll
            for (int mt = 0; mt < 4; ++mt)
                af[mt] = *(const bf16x8*)&As[(wr * 64 + mt * 16 + r16) * 64 + slot];
#pragma unroll
            for (int nt = 0; nt < 3; ++nt) {
                b1f[nt] = *(const bf16x8*)&Bs[(wc * 48 + nt * 16 + r16) * 64 + slot];
                b3f[nt] = *(const bf16x8*)&Bs[(96 + wc * 48 + nt * 16 + r16) * 64 + slot];
            }
#pragma unroll
            for (int mt = 0; mt < 4; ++mt)
#pragma unroll
                for (int nt = 0; nt < 3; ++nt) {
                    acc1[mt * 3 + nt] = MFMA16(af[mt], b1f[nt], acc1[mt * 3 + nt], 0, 0, 0);
                    acc3[mt * 3 + nt] = MFMA16(af[mt], b3f[nt], acc3[mt * 3 + nt], 0, 0, 0);
                }
        }
    }

#pragma unroll
    for (int mt = 0; mt < 4; ++mt)
#pragma unroll
        for (int nt = 0; nt < 3; ++nt) {
            const int col = n0 + wc * 48 + nt * 16 + r16;
#pragma unroll
            for (int j = 0; j < 4; ++j) {
                const int row = m0 + wr * 64 + mt * 16 + kq * 4 + j;
                const float v1 = acc1[mt * 3 + nt][j];
                const float v3 = acc3[mt * 3 + nt][j];
                const float sig = 1.0f / (1.0f + __expf(-v1));
                C[(size_t)row * ldc + col] = f2b(v1 * sig * v3);
            }
        }
}

// ---------------------------------------------------------------------------
// Flash attention v9: SPLIT-KV causal pairing -> uniform work at 4 blocks/CU.
// Softmax here is non-max-tracking (p = 2^s, l = sum p), so O and l are
// purely additive over kv tiles: kv-splitting needs only partial sums.
// Grid (NHEAD, 32, 2) = 1024 blocks (4/CU, LDS-capped), uniform 32-33
// tile-computes each:
//   s=0: sweep t=0..max(p,31-p); computes qa=p (t<=p, mask at t=p; COMPLETE
//        -> ctx) and qb=63-p (t<=31-p, partial -> scratch).  33 tilec.
//   s=1: sweep t=32-p..63-p for qb (mask at last tile; partial -> scratch).
//        32 tilec.
// fcomb_k merges: ctx[qb] = (O0+O1)/(l0+l1).
// Per-tile sync structure IDENTICAL to the verified v6/v8 loop (barrier ->
// prefetch next tile -> compute). LDS = 2*(8+8) + 8 = 40 KB.
// ---------------------------------------------------------------------------
__global__ __launch_bounds__(256)
void flash_k(const u16* __restrict__ qkv, const u16* __restrict__ vt,
             const u16* __restrict__ kp, const float* __restrict__ fc,
             const float* __restrict__ fs, u16* __restrict__ ctx,
             float* __restrict__ po, float* __restrict__ pl) {
    const int h = blockIdx.x;
    const int p = blockIdx.y;          // 0..31
    const int sid = blockIdx.z;        // 0..1
    const int qa = p, qb = 63 - p;
    const int tid = threadIdx.x;
    const int wave = tid >> 6, lane = tid & 63;
    const int r16 = lane & 15, kq = lane >> 4;

    __shared__ __align__(16) u16 Kb[2][64 * 64];   // XOR-chunk-swizzled
    __shared__ __align__(16) u16 Vb[2][64 * 64];
    __shared__ __align__(16) u16 Ps[4 * 16 * 64];  // per-wave [q][kv], swizzled

    const u16* kb = kp + (size_t)h * S_LEN * DK;
    const u16* vb = vt + (size_t)h * DK * S_LEN;
    const int srow = tid >> 3;
    const int lcol = ((tid & 7) ^ (srow & 7)) * 8;
    const int qloc = wave * 16 + r16;
    const int sw = r16 & 7;
    const int c0 = (kq ^ sw) * 8;
    const int c1 = ((4 ^ kq) ^ sw) * 8;
    const int psw = r16 & 14;
    u16* psrow = Ps + wave * 1024 + r16 * 64;

    const float SC = 0.125f * 1.44269504f;
    auto rp = [SC](u32 w, float c, float s) -> u32 {
        const float a = b2f((u16)w), b = b2f((u16)(w >> 16));
        return (u32)f2b((a * c - b * s) * SC) |
               ((u32)f2b((a * s + b * c) * SC) << 16);
    };
    auto loadq = [&](int qglob, bf16x8& q0out, bf16x8& q1out) {
        const u16* qrow = qkv + (size_t)qglob * QKV_LD + h * DK;
        uint4 uq0 = *(const uint4*)(qrow + kq * 8);
        uint4 uq1 = *(const uint4*)(qrow + 32 + kq * 8);
        const float4 c0v = *(const float4*)(fc + qglob * 32 + kq * 4);
        const float4 s0v = *(const float4*)(fs + qglob * 32 + kq * 4);
        const float4 c1v = *(const float4*)(fc + qglob * 32 + 16 + kq * 4);
        const float4 s1v = *(const float4*)(fs + qglob * 32 + 16 + kq * 4);
        uq0.x = rp(uq0.x, c0v.x, s0v.x); uq0.y = rp(uq0.y, c0v.y, s0v.y);
        uq0.z = rp(uq0.z, c0v.z, s0v.z); uq0.w = rp(uq0.w, c0v.w, s0v.w);
        uq1.x = rp(uq1.x, c1v.x, s1v.x); uq1.y = rp(uq1.y, c1v.y, s1v.y);
        uq1.z = rp(uq1.z, c1v.z, s1v.z); uq1.w = rp(uq1.w, c1v.w, s1v.w);
        q0out = __builtin_bit_cast(bf16x8, uq0);
        q1out = __builtin_bit_cast(bf16x8, uq1);
    };

    const uint4 uone = make_uint4(0x3F803F80u, 0x3F803F80u, 0x3F803F80u, 0x3F803F80u);
    const bf16x8 ones = __builtin_bit_cast(bf16x8, uone);

    // per-tile compute: S^T = K.Q^T -> p=2^s (diag-masked on last tile) ->
    // packed P^T via swizzled wave-private Ps -> O^T += V^T@P^T, l += 1@P^T
    auto tilec = [&](const u16* Ks, const u16* Vs, const bf16x8& q0f,
                     const bf16x8& q1f, f32x4 (&o)[4], f32x4& lacc, bool dmask) {
        f32x4 s[4];
#pragma unroll
        for (int nt = 0; nt < 4; ++nt) {
            s[nt] = f32x4{0.f, 0.f, 0.f, 0.f};
            const bf16x8 k0 = *(const bf16x8*)&Ks[(nt * 16 + r16) * 64 + c0];
            s[nt] = MFMA16(k0, q0f, s[nt], 0, 0, 0);
            const bf16x8 k1 = *(const bf16x8*)&Ks[(nt * 16 + r16) * 64 + c1];
            s[nt] = MFMA16(k1, q1f, s[nt], 0, 0, 0);
        }
        float pr[16];
#pragma unroll
        for (int nt = 0; nt < 4; ++nt)
#pragma unroll
            for (int j = 0; j < 4; ++j) pr[nt * 4 + j] = EXP2(s[nt][j]);
        if (dmask) {
#pragma unroll
            for (int nt = 0; nt < 4; ++nt)
#pragma unroll
                for (int j = 0; j < 4; ++j)
                    if ((nt * 16 + kq * 4 + j) > qloc) pr[nt * 4 + j] = 0.f;
        }
#pragma unroll
        for (int nt = 0; nt < 4; ++nt) {
            uint2 pk;
            pk.x = pk_trunc(pr[nt * 4 + 0], pr[nt * 4 + 1]);
            pk.y = pk_trunc(pr[nt * 4 + 2], pr[nt * 4 + 3]);
            *(uint2*)&psrow[((nt * 4 + kq) ^ psw) * 4] = pk;
        }
#pragma unroll
        for (int ks = 0; ks < 2; ++ks) {
            const bf16x8 pf = *(const bf16x8*)&psrow[((8 * ks + 2 * kq) ^ psw) * 4];
            lacc = MFMA16(ones, pf, lacc, 0, 0, 0);
            const int cv = (((ks << 2) ^ kq) ^ sw) * 8;
#pragma unroll
            for (int nt = 0; nt < 4; ++nt) {
                const bf16x8 vf = *(const bf16x8*)&Vs[(nt * 16 + r16) * 64 + cv];
                o[nt] = MFMA16(vf, pf, o[nt], 0, 0, 0);
            }
        }
    };

    float* const pob = po + ((size_t)(h * 32 + p) * 2 + sid) * 4096 + tid * 16;
    float* const plb = pl + ((size_t)(h * 32 + p) * 2 + sid) * 256 + tid;

    if (sid == 0) {
        // ---- block s=0: qa complete + qb head-partial ----
        const int qgA = qa * 64 + qloc;
        const int qgB = qb * 64 + qloc;
        bf16x8 qfA0, qfA1, qfB0, qfB1;
        loadq(qgA, qfA0, qfA1);
        loadq(qgB, qfB0, qfB1);

        f32x4 oA[4], oB[4];
#pragma unroll
        for (int i = 0; i < 4; ++i) {
            oA[i] = f32x4{0.f, 0.f, 0.f, 0.f};
            oB[i] = f32x4{0.f, 0.f, 0.f, 0.f};
        }
        f32x4 laccA = f32x4{0.f, 0.f, 0.f, 0.f};
        f32x4 laccB = f32x4{0.f, 0.f, 0.f, 0.f};

        const int tbB = 31 - p;                      // qb computed while t<=tbB
        const int tmax = (p > tbB) ? p : tbB;

        // preload tile 0 into buffer 0
#pragma unroll
        for (int i = 0; i < 2; ++i) {
            const int r = srow + i * 32;
            gll16(kb + (size_t)r * DK + lcol, Kb[0] + tid * 8 + i * 2048);
            gll16(vb + (size_t)r * S_LEN + lcol, Vb[0] + tid * 8 + i * 2048);
        }

        for (int t = 0; t <= tmax; ++t) {
            __syncthreads();
            if (t < tmax) {
                const int t1 = (t + 1) * 64;
                u16* kd = Kb[(t + 1) & 1];
                u16* vd = Vb[(t + 1) & 1];
#pragma unroll
                for (int i = 0; i < 2; ++i) {
                    const int r = srow + i * 32;
                    gll16(kb + (size_t)(t1 + r) * DK + lcol, kd + tid * 8 + i * 2048);
                    gll16(vb + (size_t)r * S_LEN + t1 + lcol, vd + tid * 8 + i * 2048);
                }
            }
            const u16* Ks = Kb[t & 1];
            const u16* Vs = Vb[t & 1];
            if (t <= tbB) tilec(Ks, Vs, qfB0, qfB1, oB, laccB, false);
            if (t <= qa)  tilec(Ks, Vs, qfA0, qfA1, oA, laccA, t == qa);
        }

        // qa is complete: normalize + write to ctx
        {
            const float inv = 1.0f / laccA[0];
            const size_t row = qgA;
#pragma unroll
            for (int nt = 0; nt < 4; ++nt) {
                uint2 pk;
                pk.x = (u32)f2b(oA[nt][0] * inv) | ((u32)f2b(oA[nt][1] * inv) << 16);
                pk.y = (u32)f2b(oA[nt][2] * inv) | ((u32)f2b(oA[nt][3] * inv) << 16);
                *(uint2*)&ctx[row * D_MODEL + h * DK + nt * 16 + kq * 4] = pk;
            }
        }
        // qb partial -> scratch
#pragma unroll
        for (int nt = 0; nt < 4; ++nt) {
            float4 v;
            v.x = oB[nt][0]; v.y = oB[nt][1]; v.z = oB[nt][2]; v.w = oB[nt][3];
            *(float4*)&pob[nt * 4] = v;
        }
        *plb = laccB[0];
    } else {
        // ---- block s=1: qb tail-partial (kv tiles 32-p .. 63-p) ----
        const int qgB = qb * 64 + qloc;
        bf16x8 qfB0, qfB1;
        loadq(qgB, qfB0, qfB1);

        f32x4 oB[4];
#pragma unroll
        for (int i = 0; i < 4; ++i) oB[i] = f32x4{0.f, 0.f, 0.f, 0.f};
        f32x4 laccB = f32x4{0.f, 0.f, 0.f, 0.f};

        const int t1s = 32 - p;    // tiles t1s .. t1s+31 (= qb)

        // preload tile t1s into buffer 0
        {
            const int tb = t1s * 64;
#pragma unroll
            for (int i = 0; i < 2; ++i) {
                const int r = srow + i * 32;
                gll16(kb + (size_t)(tb + r) * DK + lcol, Kb[0] + tid * 8 + i * 2048);
                gll16(vb + (size_t)r * S_LEN + tb + lcol, Vb[0] + tid * 8 + i * 2048);
            }
        }

        for (int i = 0; i < 32; ++i) {
            __syncthreads();
            if (i < 31) {
                const int t1 = (t1s + i + 1) * 64;
                u16* kd = Kb[(i + 1) & 1];
                u16* vd = Vb[(i + 1) & 1];
#pragma unroll
                for (int j = 0; j < 2; ++j) {
                    const int r = srow + j * 32;
                    gll16(kb + (size_t)(t1 + r) * DK + lcol, kd + tid * 8 + j * 2048);
                    gll16(vb + (size_t)r * S_LEN + t1 + lcol, vd + tid * 8 + j * 2048);
                }
            }
            const u16* Ks = Kb[i & 1];
            const u16* Vs = Vb[i & 1];
            tilec(Ks, Vs, qfB0, qfB1, oB, laccB, i == 31);   // last tile == qb
        }

#pragma unroll
        for (int nt = 0; nt < 4; ++nt) {
            float4 v;
            v.x = oB[nt][0]; v.y = oB[nt][1]; v.z = oB[nt][2]; v.w = oB[nt][3];
            *(float4*)&pob[nt * 4] = v;
        }
        *plb = laccB[0];
    }
}

// ---------------------------------------------------------------------------
// Combine kernel: ctx rows of qb = 63-p  <-  (O0+O1)/(l0+l1).
// Same lane->element mapping as flash_k's epilogue. 512 blocks x 256 thr.
// ---------------------------------------------------------------------------
__global__ __launch_bounds__(256)
void fcomb_k(const float* __restrict__ po, const float* __restrict__ pl,
             u16* __restrict__ ctx) {
    const int hp = blockIdx.x;         // h*32 + p
    const int h = hp >> 5, p = hp & 31;
    const int tid = threadIdx.x;
    const int wave = tid >> 6, lane = tid & 63;
    const int r16 = lane & 15, kq = lane >> 4;

    const float l = pl[(size_t)hp * 512 + tid] + pl[(size_t)hp * 512 + 256 + tid];
    const float inv = 1.0f / l;
    const float* o0 = po + (size_t)hp * 8192 + tid * 16;
    const float* o1 = o0 + 4096;
    const size_t row = (size_t)(63 - p) * 64 + wave * 16 + r16;

#pragma unroll
    for (int nt = 0; nt < 4; ++nt) {
        const float4 a = *(const float4*)&o0[nt * 4];
        const float4 b = *(const float4*)&o1[nt * 4];
        uint2 pk;
        pk.x = (u32)f2b((a.x + b.x) * inv) | ((u32)f2b((a.y + b.y) * inv) << 16);
        pk.y = (u32)f2b((a.z + b.z) * inv) | ((u32)f2b((a.w + b.w) * inv) << 16);
        *(uint2*)&ctx[row * D_MODEL + h * DK + nt * 16 + kq * 4] = pk;
    }
}

// ---------------------------------------------------------------------------
extern "C" void kernel_launch(void* const* d_in, const int* in_sizes, int n_in,
                              void* d_out, int out_size, void* d_ws, size_t ws_size,
                              hipStream_t stream) {
    const float* x    = (const float*)d_in[0];
    const float* fcos = (const float*)d_in[1];
    const float* fsin = (const float*)d_in[2];
    const float* Wq = (const float*)d_in[4];
    const float* Wk = (const float*)d_in[5];
    const float* Wv = (const float*)d_in[6];
    const float* Wo = (const float*)d_in[7];
    const float* ln1 = (const float*)d_in[8];
    const float* ln2 = (const float*)d_in[9];
    const float* w1 = (const float*)d_in[10];
    const float* w2 = (const float*)d_in[11];
    const float* w3 = (const float*)d_in[12];
    float* out = (float*)d_out;

    char* ws = (char*)d_ws;
    size_t off = 0;
    auto alloc = [&](size_t bytes) -> char* {
        char* p = ws + off;
        off += (bytes + 255) & ~(size_t)255;
        return p;
    };
    u16* hb    = (u16*)alloc((size_t)S_LEN * D_MODEL * 2);
    u16* wqkvt = (u16*)alloc((size_t)QKV_LD * D_MODEL * 2);  // [3072][1024]
    u16* wot   = (u16*)alloc((size_t)D_MODEL * D_MODEL * 2);
    u16* qkvb  = (u16*)alloc((size_t)S_LEN * QKV_LD * 2);    // [4096][3072]
    u16* vt    = (u16*)alloc((size_t)S_LEN * D_MODEL * 2);   // [H][DK][S]
    u16* kpack = (u16*)alloc((size_t)S_LEN * D_MODEL * 2);   // [H][S][DK]
    u16* ctxb  = (u16*)alloc((size_t)S_LEN * D_MODEL * 2);
    float* x2  = (float*)alloc((size_t)S_LEN * D_MODEL * 4);
    u16* h2b   = (u16*)alloc((size_t)S_LEN * D_MODEL * 2);
    u16* w1t   = (u16*)alloc((size_t)HIDP * D_MODEL * 2);    // [2880][1024]
    u16* w3t   = (u16*)alloc((size_t)HIDP * D_MODEL * 2);
    u16* w2t   = (u16*)alloc((size_t)D_MODEL * HIDP * 2);    // [1024][2880]
    u16* ffb   = (u16*)alloc((size_t)S_LEN * HIDP * 2);      // [4096][2880]
    float* po  = (float*)alloc((size_t)512 * 8192 * 4);      // qb partial O
    float* pl  = (float*)alloc((size_t)512 * 512 * 4);       // qb partial l

    const dim3 tb32(32, 8);

    // weight transposes + rmsnorm(x, ln1), one launch
    prep_k<<<16832, 256, 0, stream>>>(
        Wq, Wk, Wv, Wo, w1, w3, w2,
        wqkvt, wqkvt + (size_t)D_MODEL * D_MODEL,
        wqkvt + (size_t)2 * D_MODEL * D_MODEL, wot, w1t, w3t, w2t,
        x, ln1, hb);

    // QKV = h @ [Wq|Wk|Wv]   (one 4096x3072x1024 GEMM, raw Q/K)
    gemm128<0><<<dim3(QKV_LD / 128, S_LEN / 128), 256, 0, stream>>>(
        hb, D_MODEL, wqkvt, D_MODEL, qkvb, QKV_LD, D_MODEL, nullptr);

    // K packed (+RoPE) + V transposed per head
    packkv_k<<<dim3(S_LEN / 32, DK / 32, NHEAD), tb32, 0, stream>>>(
        qkvb, fcos, fsin, vt, kpack);

    // flash attention: split-kv causal pairing, 1024 uniform blocks
    flash_k<<<dim3(NHEAD, 32, 2), 256, 0, stream>>>(
        qkvb, vt, kpack, fcos, fsin, ctxb, po, pl);

    // combine qb partials
    fcomb_k<<<512, 256, 0, stream>>>(po, pl, ctxb);

    // x2 = x + ctx @ Wo
    gemm64r<<<dim3(D_MODEL / 64, S_LEN / 128), 256, 0, stream>>>(
        ctxb, D_MODEL, wot, D_MODEL, x2, D_MODEL, D_MODEL, x);

    // h2 = rmsnorm(x2, ln2)
    rmsnorm_k<<<S_LEN, 256, 0, stream>>>(x2, ln2, h2b);

    // ff = silu(h2@w1) * (h2@w3)
    gemm_dual96x<<<dim3(HIDP / 96, S_LEN / 128), 256, 0, stream>>>(
        h2b, D_MODEL, w1t, w3t, D_MODEL, ffb, HIDP, D_MODEL);

    // out = x2 + ff @ w2
    gemm64r<<<dim3(D_MODEL / 64, S_LEN / 128), 256, 0, stream>>>(
        ffb, HIDP, w2t, HIDP, out, D_MODEL, HIDP, x2);
}

// Round 6
// 381.915 us; speedup vs baseline: 1.1190x; 1.1156x over previous
//
#include <hip/hip_runtime.h>

#define S_LEN 4096
#define D_MODEL 1024
#define NHEAD 16
#define DK 64
#define HID 2730
#define HIDP 2880
#define QKV_LD 3072

typedef unsigned short u16;
typedef unsigned int u32;
typedef __bf16 bf16x8 __attribute__((ext_vector_type(8)));
typedef float f32x4 __attribute__((ext_vector_type(4)));

#define MFMA16 __builtin_amdgcn_mfma_f32_16x16x32_bf16
// raw v_exp_f32 (2^x): scores bounded (|s| < ~30), no OCML guard code needed
#define EXP2 __builtin_amdgcn_exp2f

__device__ __forceinline__ float b2f(u16 u) {
    return __builtin_bit_cast(float, (u32)u << 16);
}
__device__ __forceinline__ u16 f2b(float f) {
    u32 u = __builtin_bit_cast(u32, f);
    u += 0x7FFF + ((u >> 16) & 1);
    return (u16)(u >> 16);
}
// pack two f32 -> two bf16 (truncate) in one v_perm_b32
__device__ __forceinline__ u32 pk_trunc(float lo, float hi) {
    return __builtin_amdgcn_perm(__builtin_bit_cast(u32, hi),
                                 __builtin_bit_cast(u32, lo), 0x07060302u);
}
// async global->LDS, 16B per lane; dest must be wave-uniform base + lane*16
__device__ __forceinline__ void gll16(const u16* g, u16* l) {
    __builtin_amdgcn_global_load_lds(
        (__attribute__((address_space(1))) void*)(g),
        (__attribute__((address_space(3))) void*)(l),
        16, 0, 0);
}

// ---------------------------------------------------------------------------
// Prep: 7 weight transposes (fp32->bf16, zero-pad) + rmsnorm(x, ln1) in ONE
// launch. Flat grid, 256-thread blocks. Blocks 0..12735 = tcast segments;
// blocks 12736..16831 = rmsnorm rows.  (HIDP = 2880 = 30*96)
// ---------------------------------------------------------------------------
__global__ __launch_bounds__(256)
void prep_k(const float* s0, const float* s1, const float* s2,
            const float* s3, const float* s4, const float* s5,
            const float* s6, u16* d0, u16* d1, u16* d2, u16* d3,
            u16* d4, u16* d5, u16* d6,
            const float* __restrict__ x, const float* __restrict__ ln1,
            u16* __restrict__ hb) {
    __shared__ float t[32][33];
    __shared__ float red[4];
    const int bid = blockIdx.x;
    const int tid = threadIdx.x;

    if (bid >= 12736) {   // ---- rmsnorm path ----
        const int row = bid - 12736;
        const float4 v = ((const float4*)(x + (size_t)row * D_MODEL))[tid];
        float ss = v.x * v.x + v.y * v.y + v.z * v.z + v.w * v.w;
        for (int o = 32; o; o >>= 1) ss += __shfl_down(ss, o);
        if ((tid & 63) == 0) red[tid >> 6] = ss;
        __syncthreads();
        const float tot = red[0] + red[1] + red[2] + red[3];
        const float rs = rsqrtf(tot * (1.0f / D_MODEL) + 1e-6f);
        const float4 wv = ((const float4*)ln1)[tid];
        u16* op = hb + (size_t)row * D_MODEL + tid * 4;
        u32 p0 = (u32)f2b(v.x * rs * wv.x) | ((u32)f2b(v.y * rs * wv.y) << 16);
        u32 p1 = (u32)f2b(v.z * rs * wv.z) | ((u32)f2b(v.w * rs * wv.w) << 16);
        uint2 pk; pk.x = p0; pk.y = p1;
        *(uint2*)op = pk;
        return;
    }

    // ---- transpose path ----
    const float* srcs[7] = {s0, s1, s2, s3, s4, s5, s6};
    u16* dsts[7] = {d0, d1, d2, d3, d4, d5, d6};
    const int RR[7] = {1024, 1024, 1024, 1024, 1024, 1024, 2730};
    const int CC[7] = {1024, 1024, 1024, 1024, 2730, 2730, 1024};
    const int OC[7] = {1024, 1024, 1024, 1024, 1024, 1024, 2880};
    const int XD[7] = {32, 32, 32, 32, 32, 32, 90};

    int seg, start;
    if (bid < 4096)      { seg = bid >> 10; start = seg << 10; }
    else if (bid < 6976) { seg = 4; start = 4096; }
    else if (bid < 9856) { seg = 5; start = 6976; }
    else                 { seg = 6; start = 9856; }
    const int local = bid - start;
    const int bx = local % XD[seg], byy = local / XD[seg];
    const float* in = srcs[seg];
    u16* out = dsts[seg];
    const int R = RR[seg], C = CC[seg], outC = OC[seg];

    const int r0 = byy * 32;
    const int c0 = bx * 32;
    const int tx = tid & 31, ty = tid >> 5;
#pragma unroll
    for (int j = 0; j < 4; ++j) {
        int ir = c0 + ty + j * 8;
        int ic = r0 + tx;
        t[ty + j * 8][tx] = (ir < R && ic < C) ? in[(size_t)ir * C + ic] : 0.0f;
    }
    __syncthreads();
#pragma unroll
    for (int j = 0; j < 4; ++j)
        out[(size_t)(r0 + ty + j * 8) * outC + c0 + tx] = f2b(t[tx][ty + j * 8]);
}

// ---------------------------------------------------------------------------
// RMSNorm (standalone, for x2 -> h2b)
// ---------------------------------------------------------------------------
__global__ __launch_bounds__(256)
void rmsnorm_k(const float* __restrict__ x, const float* __restrict__ w,
               u16* __restrict__ out) {
    const int row = blockIdx.x;
    const int tid = threadIdx.x;
    const float4 v = ((const float4*)(x + (size_t)row * D_MODEL))[tid];
    float ss = v.x * v.x + v.y * v.y + v.z * v.z + v.w * v.w;
    for (int o = 32; o; o >>= 1) ss += __shfl_down(ss, o);
    __shared__ float red[4];
    if ((tid & 63) == 0) red[tid >> 6] = ss;
    __syncthreads();
    const float tot = red[0] + red[1] + red[2] + red[3];
    const float rs = rsqrtf(tot * (1.0f / D_MODEL) + 1e-6f);
    const float4 wv = ((const float4*)w)[tid];
    u16* op = out + (size_t)row * D_MODEL + tid * 4;
    u32 p0 = (u32)f2b(v.x * rs * wv.x) | ((u32)f2b(v.y * rs * wv.y) << 16);
    u32 p1 = (u32)f2b(v.z * rs * wv.z) | ((u32)f2b(v.w * rs * wv.w) << 16);
    uint2 pk; pk.x = p0; pk.y = p1;
    *(uint2*)op = pk;
}

// ---------------------------------------------------------------------------
// Pack K/V per head, K-RoPE fused:
//   kp[h][s][d] = rope(qkv[s][1024 + h*64 + d])
//   vt[h][d][s] = qkv[s][2048 + h*64 + d]
// ---------------------------------------------------------------------------
__global__ __launch_bounds__(256)
void packkv_k(const u16* __restrict__ qkv, const float* __restrict__ fc,
              const float* __restrict__ fs, u16* __restrict__ vt,
              u16* __restrict__ kp) {
    __shared__ u16 t[32][33];
    const int h = blockIdx.z;
    const int t0 = blockIdx.x * 32;
    const int d0 = blockIdx.y * 32;
    const int tx = threadIdx.x, ty = threadIdx.y;
#pragma unroll
    for (int j = 0; j < 4; ++j)
        t[ty + j * 8][tx] =
            qkv[(size_t)(t0 + ty + j * 8) * QKV_LD + 2 * D_MODEL + h * DK + d0 + tx];

    const int id = ty * 32 + tx;
    const int sA = t0 + (id >> 3);
    const int dA = d0 + (id & 7) * 4;
    uint2 kvp = *(const uint2*)(qkv + (size_t)sA * QKV_LD + D_MODEL + h * DK + dA);
    const int fi = sA * 32 + (dA >> 1);
    const float cc0 = fc[fi], ss0 = fs[fi];
    const float cc1 = fc[fi + 1], ss1 = fs[fi + 1];
    auto rpk = [](u32 w, float c, float s) -> u32 {
        const float a = b2f((u16)w), b = b2f((u16)(w >> 16));
        return (u32)f2b(a * c - b * s) | ((u32)f2b(a * s + b * c) << 16);
    };
    kvp.x = rpk(kvp.x, cc0, ss0);
    kvp.y = rpk(kvp.y, cc1, ss1);
    *(uint2*)(kp + ((size_t)h * S_LEN + sA) * DK + dA) = kvp;

    __syncthreads();
#pragma unroll
    for (int j = 0; j < 4; ++j)
        vt[(size_t)h * DK * S_LEN + (size_t)(d0 + ty + j * 8) * S_LEN + t0 + tx] =
            t[tx][ty + j * 8];
}

// ---------------------------------------------------------------------------
// 128x128 GEMM, BK=64 + XOR-swizzled staging (same recipe as gemm_dual96x):
// halves the vmcnt(0)+barrier drain count vs BK=32 (the 2-phase critical
// path), 32 MFMA per barrier-pair. Pre-swizzled global source chunk
// (c8 ^ row&7), linear LDS dest, XOR'd read slot. LDS = 32 KB.
// ---------------------------------------------------------------------------
template <int EPI>
__global__ __launch_bounds__(256)
void gemm128(const u16* __restrict__ A, int lda, const u16* __restrict__ Bt, int ldb,
             void* __restrict__ C, int ldc, int K, const float* __restrict__ resid) {
    const int m0 = blockIdx.y * 128, n0 = blockIdx.x * 128;
    const int tid = threadIdx.x;
    const int wave = tid >> 6, lane = tid & 63;
    const int wr = wave >> 1, wc = wave & 1;
    const int r16 = lane & 15, kq = lane >> 4;

    __shared__ __align__(16) u16 As[128 * 64];
    __shared__ __align__(16) u16 Bs[128 * 64];

    const int srow = tid >> 3;                       // 0..31
    const int scol = ((tid & 7) ^ (srow & 7)) * 8;   // pre-swizzled source col
    const u16* ag0 = A + (size_t)(m0 +  0 + srow) * lda + scol;
    const u16* ag1 = A + (size_t)(m0 + 32 + srow) * lda + scol;
    const u16* ag2 = A + (size_t)(m0 + 64 + srow) * lda + scol;
    const u16* ag3 = A + (size_t)(m0 + 96 + srow) * lda + scol;
    const u16* bg0 = Bt + (size_t)(n0 +  0 + srow) * ldb + scol;
    const u16* bg1 = Bt + (size_t)(n0 + 32 + srow) * ldb + scol;
    const u16* bg2 = Bt + (size_t)(n0 + 64 + srow) * ldb + scol;
    const u16* bg3 = Bt + (size_t)(n0 + 96 + srow) * ldb + scol;
    u16* const ad = As + tid * 8;
    u16* const bd = Bs + tid * 8;

    f32x4 acc[16];
#pragma unroll
    for (int i = 0; i < 16; ++i) acc[i] = f32x4{0.f, 0.f, 0.f, 0.f};

    const int rsw = r16 & 7;
    for (int k0 = 0; k0 < K; k0 += 64) {
        __syncthreads();
        gll16(ag0 + k0, ad);
        gll16(ag1 + k0, ad + 2048);
        gll16(ag2 + k0, ad + 4096);
        gll16(ag3 + k0, ad + 6144);
        gll16(bg0 + k0, bd);
        gll16(bg1 + k0, bd + 2048);
        gll16(bg2 + k0, bd + 4096);
        gll16(bg3 + k0, bd + 6144);
        __syncthreads();
#pragma unroll
        for (int ks = 0; ks < 2; ++ks) {
            const int slot = (((ks << 2) | kq) ^ rsw) * 8;
            bf16x8 af[4], bf[4];
#pragma unroll
            for (int mt = 0; mt < 4; ++mt)
                af[mt] = *(const bf16x8*)&As[(wr * 64 + mt * 16 + r16) * 64 + slot];
#pragma unroll
            for (int nt = 0; nt < 4; ++nt)
                bf[nt] = *(const bf16x8*)&Bs[(wc * 64 + nt * 16 + r16) * 64 + slot];
#pragma unroll
            for (int mt = 0; mt < 4; ++mt)
#pragma unroll
                for (int nt = 0; nt < 4; ++nt)
                    acc[mt * 4 + nt] = MFMA16(af[mt], bf[nt], acc[mt * 4 + nt], 0, 0, 0);
        }
    }

#pragma unroll
    for (int mt = 0; mt < 4; ++mt) {
#pragma unroll
        for (int nt = 0; nt < 4; ++nt) {
            const int col = n0 + wc * 64 + nt * 16 + r16;
#pragma unroll
            for (int j = 0; j < 4; ++j) {
                const int row = m0 + wr * 64 + mt * 16 + kq * 4 + j;
                if (EPI == 0) {
                    ((u16*)C)[(size_t)row * ldc + col] = f2b(acc[mt * 4 + nt][j]);
                } else {
                    ((float*)C)[(size_t)row * ldc + col] =
                        resid[(size_t)row * ldc + col] + acc[mt * 4 + nt][j];
                }
            }
        }
    }
}

// ---------------------------------------------------------------------------
// 128(M) x 64(N) GEMM + fp32 residual epilogue, BK=64 + XOR-swizzle.
// 16 MFMA per barrier-pair (was 8). LDS = 16 + 8 = 24 KB.
// ---------------------------------------------------------------------------
__global__ __launch_bounds__(256)
void gemm64r(const u16* __restrict__ A, int lda, const u16* __restrict__ Bt, int ldb,
             float* __restrict__ C, int ldc, int K, const float* __restrict__ resid) {
    const int m0 = blockIdx.y * 128, n0 = blockIdx.x * 64;
    const int tid = threadIdx.x;
    const int wave = tid >> 6, lane = tid & 63;
    const int r16 = lane & 15, kq = lane >> 4;

    __shared__ __align__(16) u16 As[128 * 64];
    __shared__ __align__(16) u16 Bs[64 * 64];

    const int srow = tid >> 3;
    const int scol = ((tid & 7) ^ (srow & 7)) * 8;
    const u16* ag0 = A + (size_t)(m0 +  0 + srow) * lda + scol;
    const u16* ag1 = A + (size_t)(m0 + 32 + srow) * lda + scol;
    const u16* ag2 = A + (size_t)(m0 + 64 + srow) * lda + scol;
    const u16* ag3 = A + (size_t)(m0 + 96 + srow) * lda + scol;
    const u16* bg0 = Bt + (size_t)(n0 +  0 + srow) * ldb + scol;
    const u16* bg1 = Bt + (size_t)(n0 + 32 + srow) * ldb + scol;
    u16* const ad = As + tid * 8;
    u16* const bd = Bs + tid * 8;

    f32x4 acc[8];
#pragma unroll
    for (int i = 0; i < 8; ++i) acc[i] = f32x4{0.f, 0.f, 0.f, 0.f};

    const int rsw = r16 & 7;
    for (int k0 = 0; k0 < K; k0 += 64) {
        __syncthreads();
        gll16(ag0 + k0, ad);
        gll16(ag1 + k0, ad + 2048);
        gll16(ag2 + k0, ad + 4096);
        gll16(ag3 + k0, ad + 6144);
        gll16(bg0 + k0, bd);
        gll16(bg1 + k0, bd + 2048);
        __syncthreads();
#pragma unroll
        for (int ks = 0; ks < 2; ++ks) {
            const int slot = (((ks << 2) | kq) ^ rsw) * 8;
            bf16x8 af[2], bf[4];
#pragma unroll
            for (int mt = 0; mt < 2; ++mt)
                af[mt] = *(const bf16x8*)&As[(wave * 32 + mt * 16 + r16) * 64 + slot];
#pragma unroll
            for (int nt = 0; nt < 4; ++nt)
                bf[nt] = *(const bf16x8*)&Bs[(nt * 16 + r16) * 64 + slot];
#pragma unroll
            for (int mt = 0; mt < 2; ++mt)
#pragma unroll
                for (int nt = 0; nt < 4; ++nt)
                    acc[mt * 4 + nt] = MFMA16(af[mt], bf[nt], acc[mt * 4 + nt], 0, 0, 0);
        }
    }

#pragma unroll
    for (int mt = 0; mt < 2; ++mt)
#pragma unroll
        for (int nt = 0; nt < 4; ++nt) {
            const int col = n0 + nt * 16 + r16;
#pragma unroll
            for (int j = 0; j < 4; ++j) {
                const int row = m0 + wave * 32 + mt * 16 + kq * 4 + j;
                C[(size_t)row * ldc + col] =
                    resid[(size_t)row * ldc + col] + acc[mt * 4 + nt][j];
            }
        }
}

// ---------------------------------------------------------------------------
// FFN dual GEMM v3: tile 128(M) x 96(N per matrix), BK=64 (verified win).
// ---------------------------------------------------------------------------
__global__ __launch_bounds__(256, 3)
void gemm_dual96x(const u16* __restrict__ A, int lda,
                  const u16* __restrict__ B1, const u16* __restrict__ B3, int ldb,
                  u16* __restrict__ C, int ldc, int K) {
    const int m0 = blockIdx.y * 128, n0 = blockIdx.x * 96;
    const int tid = threadIdx.x;
    const int wave = tid >> 6, lane = tid & 63;
    const int wr = wave >> 1, wc = wave & 1;
    const int r16 = lane & 15, kq = lane >> 4;

    __shared__ __align__(16) u16 As[128 * 64];   // swizzled rows
    __shared__ __align__(16) u16 Bs[192 * 64];   // rows 0-95 = B1, 96-191 = B3

    const int srow = tid >> 3;                       // 0..31 (row within call)
    const int scol = ((tid & 7) ^ (srow & 7)) * 8;   // pre-swizzled source col
    const u16* ag0 = A + (size_t)(m0 +  0 + srow) * lda + scol;
    const u16* ag1 = A + (size_t)(m0 + 32 + srow) * lda + scol;
    const u16* ag2 = A + (size_t)(m0 + 64 + srow) * lda + scol;
    const u16* ag3 = A + (size_t)(m0 + 96 + srow) * lda + scol;
    const u16* bg0 = B1 + (size_t)(n0 +  0 + srow) * ldb + scol;
    const u16* bg1 = B1 + (size_t)(n0 + 32 + srow) * ldb + scol;
    const u16* bg2 = B1 + (size_t)(n0 + 64 + srow) * ldb + scol;
    const u16* bg3 = B3 + (size_t)(n0 +  0 + srow) * ldb + scol;
    const u16* bg4 = B3 + (size_t)(n0 + 32 + srow) * ldb + scol;
    const u16* bg5 = B3 + (size_t)(n0 + 64 + srow) * ldb + scol;
    u16* const ad = As + tid * 8;
    u16* const bd = Bs + tid * 8;

    f32x4 acc1[12], acc3[12];
#pragma unroll
    for (int i = 0; i < 12; ++i) {
        acc1[i] = f32x4{0.f, 0.f, 0.f, 0.f};
        acc3[i] = f32x4{0.f, 0.f, 0.f, 0.f};
    }

    const int rsw = r16 & 7;
    for (int k0 = 0; k0 < K; k0 += 64) {
        __syncthreads();
        gll16(ag0 + k0, ad);
        gll16(ag1 + k0, ad + 2048);
        gll16(ag2 + k0, ad + 4096);
        gll16(ag3 + k0, ad + 6144);
        gll16(bg0 + k0, bd);
        gll16(bg1 + k0, bd + 2048);
        gll16(bg2 + k0, bd + 4096);
        gll16(bg3 + k0, bd + 6144);
        gll16(bg4 + k0, bd + 8192);
        gll16(bg5 + k0, bd + 10240);
        __syncthreads();
#pragma unroll
        for (int ks = 0; ks < 2; ++ks) {
            const int slot = (((ks << 2) | kq) ^ rsw) * 8;
            bf16x8 af[4], b1f[3], b3f[3];
#pragma unroll
            for (int mt = 0; mt < 4; ++mt)
                af[mt] = *(const bf16x8*)&As[(wr * 64 + mt * 16 + r16) * 64 + slot];
#pragma unroll
            for (int nt = 0; nt < 3; ++nt) {
                b1f[nt] = *(const bf16x8*)&Bs[(wc * 48 + nt * 16 + r16) * 64 + slot];
                b3f[nt] = *(const bf16x8*)&Bs[(96 + wc * 48 + nt * 16 + r16) * 64 + slot];
            }
#pragma unroll
            for (int mt = 0; mt < 4; ++mt)
#pragma unroll
                for (int nt = 0; nt < 3; ++nt) {
                    acc1[mt * 3 + nt] = MFMA16(af[mt], b1f[nt], acc1[mt * 3 + nt], 0, 0, 0);
                    acc3[mt * 3 + nt] = MFMA16(af[mt], b3f[nt], acc3[mt * 3 + nt], 0, 0, 0);
                }
        }
    }

#pragma unroll
    for (int mt = 0; mt < 4; ++mt)
#pragma unroll
        for (int nt = 0; nt < 3; ++nt) {
            const int col = n0 + wc * 48 + nt * 16 + r16;
#pragma unroll
            for (int j = 0; j < 4; ++j) {
                const int row = m0 + wr * 64 + mt * 16 + kq * 4 + j;
                const float v1 = acc1[mt * 3 + nt][j];
                const float v3 = acc3[mt * 3 + nt][j];
                const float sig = 1.0f / (1.0f + __expf(-v1));
                C[(size_t)row * ldc + col] = f2b(v1 * sig * v3);
            }
        }
}

// ---------------------------------------------------------------------------
// Flash attention v8 (verified 74 us): interleaved causal pairing, sync
// structure identical to v6. Block (h, pair) handles q-tiles qa=pair and
// qb=63-pair in ONE kv sweep t=0..qb: per tile, compute the qb part always
// and the qa part while t<=qa -> uniform 65 tile-computes per block.
// Grid 512. LDS = 2*(8+8) + 8 = 40 KB.
// ---------------------------------------------------------------------------
__global__ __launch_bounds__(256)
void flash_k(const u16* __restrict__ qkv, const u16* __restrict__ vt,
             const u16* __restrict__ kp, const float* __restrict__ fc,
             const float* __restrict__ fs, u16* __restrict__ ctx) {
    const int h = blockIdx.x;
    const int pair = blockIdx.y;       // 0..31
    const int qa = pair, qb = 63 - pair;
    const int tid = threadIdx.x;
    const int wave = tid >> 6, lane = tid & 63;
    const int r16 = lane & 15, kq = lane >> 4;

    __shared__ __align__(16) u16 Kb[2][64 * 64];   // XOR-chunk-swizzled
    __shared__ __align__(16) u16 Vb[2][64 * 64];
    __shared__ __align__(16) u16 Ps[4 * 16 * 64];  // per-wave [q][kv], swizzled

    const u16* kb = kp + (size_t)h * S_LEN * DK;
    const u16* vb = vt + (size_t)h * DK * S_LEN;
    const int srow = tid >> 3;
    const int lcol = ((tid & 7) ^ (srow & 7)) * 8;
    const int qloc = wave * 16 + r16;
    const int sw = r16 & 7;
    const int c0 = (kq ^ sw) * 8;
    const int c1 = ((4 ^ kq) ^ sw) * 8;
    const int psw = r16 & 14;
    u16* psrow = Ps + wave * 1024 + r16 * 64;

    const float SC = 0.125f * 1.44269504f;
    auto rp = [SC](u32 w, float c, float s) -> u32 {
        const float a = b2f((u16)w), b = b2f((u16)(w >> 16));
        return (u32)f2b((a * c - b * s) * SC) |
               ((u32)f2b((a * s + b * c) * SC) << 16);
    };
    // Q: raw load + RoPE + scale, in registers (for both q-tiles)
    auto loadq = [&](int qglob, bf16x8& q0out, bf16x8& q1out) {
        const u16* qrow = qkv + (size_t)qglob * QKV_LD + h * DK;
        uint4 uq0 = *(const uint4*)(qrow + kq * 8);
        uint4 uq1 = *(const uint4*)(qrow + 32 + kq * 8);
        const float4 c0v = *(const float4*)(fc + qglob * 32 + kq * 4);
        const float4 s0v = *(const float4*)(fs + qglob * 32 + kq * 4);
        const float4 c1v = *(const float4*)(fc + qglob * 32 + 16 + kq * 4);
        const float4 s1v = *(const float4*)(fs + qglob * 32 + 16 + kq * 4);
        uq0.x = rp(uq0.x, c0v.x, s0v.x); uq0.y = rp(uq0.y, c0v.y, s0v.y);
        uq0.z = rp(uq0.z, c0v.z, s0v.z); uq0.w = rp(uq0.w, c0v.w, s0v.w);
        uq1.x = rp(uq1.x, c1v.x, s1v.x); uq1.y = rp(uq1.y, c1v.y, s1v.y);
        uq1.z = rp(uq1.z, c1v.z, s1v.z); uq1.w = rp(uq1.w, c1v.w, s1v.w);
        q0out = __builtin_bit_cast(bf16x8, uq0);
        q1out = __builtin_bit_cast(bf16x8, uq1);
    };
    const int qgA = qa * 64 + qloc;
    const int qgB = qb * 64 + qloc;
    bf16x8 qfA0, qfA1, qfB0, qfB1;
    loadq(qgA, qfA0, qfA1);
    loadq(qgB, qfB0, qfB1);

    f32x4 oA[4], oB[4];
#pragma unroll
    for (int i = 0; i < 4; ++i) {
        oA[i] = f32x4{0.f, 0.f, 0.f, 0.f};
        oB[i] = f32x4{0.f, 0.f, 0.f, 0.f};
    }
    f32x4 laccA = f32x4{0.f, 0.f, 0.f, 0.f};
    f32x4 laccB = f32x4{0.f, 0.f, 0.f, 0.f};
    const uint4 uone = make_uint4(0x3F803F80u, 0x3F803F80u, 0x3F803F80u, 0x3F803F80u);
    const bf16x8 ones = __builtin_bit_cast(bf16x8, uone);

    // per-tile compute: S^T = K.Q^T -> p=2^s (diag-masked on last tile) ->
    // packed P^T via swizzled wave-private Ps -> O^T += V^T@P^T, l += 1@P^T
    auto tilec = [&](const u16* Ks, const u16* Vs, const bf16x8& q0f,
                     const bf16x8& q1f, f32x4 (&o)[4], f32x4& lacc, bool dmask) {
        f32x4 s[4];
#pragma unroll
        for (int nt = 0; nt < 4; ++nt) {
            s[nt] = f32x4{0.f, 0.f, 0.f, 0.f};
            const bf16x8 k0 = *(const bf16x8*)&Ks[(nt * 16 + r16) * 64 + c0];
            s[nt] = MFMA16(k0, q0f, s[nt], 0, 0, 0);
            const bf16x8 k1 = *(const bf16x8*)&Ks[(nt * 16 + r16) * 64 + c1];
            s[nt] = MFMA16(k1, q1f, s[nt], 0, 0, 0);
        }
        float pr[16];
#pragma unroll
        for (int nt = 0; nt < 4; ++nt)
#pragma unroll
            for (int j = 0; j < 4; ++j) pr[nt * 4 + j] = EXP2(s[nt][j]);
        if (dmask) {
#pragma unroll
            for (int nt = 0; nt < 4; ++nt)
#pragma unroll
                for (int j = 0; j < 4; ++j)
                    if ((nt * 16 + kq * 4 + j) > qloc) pr[nt * 4 + j] = 0.f;
        }
#pragma unroll
        for (int nt = 0; nt < 4; ++nt) {
            uint2 pk;
            pk.x = pk_trunc(pr[nt * 4 + 0], pr[nt * 4 + 1]);
            pk.y = pk_trunc(pr[nt * 4 + 2], pr[nt * 4 + 3]);
            *(uint2*)&psrow[((nt * 4 + kq) ^ psw) * 4] = pk;
        }
#pragma unroll
        for (int ks = 0; ks < 2; ++ks) {
            const bf16x8 pf = *(const bf16x8*)&psrow[((8 * ks + 2 * kq) ^ psw) * 4];
            lacc = MFMA16(ones, pf, lacc, 0, 0, 0);
            const int cv = (((ks << 2) ^ kq) ^ sw) * 8;
#pragma unroll
            for (int nt = 0; nt < 4; ++nt) {
                const bf16x8 vf = *(const bf16x8*)&Vs[(nt * 16 + r16) * 64 + cv];
                o[nt] = MFMA16(vf, pf, o[nt], 0, 0, 0);
            }
        }
    };

    // preload tile 0 into buffer 0
#pragma unroll
    for (int i = 0; i < 2; ++i) {
        const int r = srow + i * 32;
        gll16(kb + (size_t)r * DK + lcol, Kb[0] + tid * 8 + i * 2048);
        gll16(vb + (size_t)r * S_LEN + lcol, Vb[0] + tid * 8 + i * 2048);
    }

    for (int t = 0; t <= qb; ++t) {
        __syncthreads();   // drains tile-t loads; all waves done with buf[(t+1)&1]
        if (t < qb) {      // issue next-tile loads NOW; they overlap compute below
            const int t1 = (t + 1) * 64;
            u16* kd = Kb[(t + 1) & 1];
            u16* vd = Vb[(t + 1) & 1];
#pragma unroll
            for (int i = 0; i < 2; ++i) {
                const int r = srow + i * 32;
                gll16(kb + (size_t)(t1 + r) * DK + lcol, kd + tid * 8 + i * 2048);
                gll16(vb + (size_t)r * S_LEN + t1 + lcol, vd + tid * 8 + i * 2048);
            }
        }
        const u16* Ks = Kb[t & 1];
        const u16* Vs = Vb[t & 1];

        tilec(Ks, Vs, qfB0, qfB1, oB, laccB, t == qb);
        if (t <= qa)
            tilec(Ks, Vs, qfA0, qfA1, oA, laccA, t == qa);
    }

    // l: every lacc element equals the full sum for column q=r16
    auto wout = [&](f32x4 (&o)[4], float lsum, int qg) {
        const float inv = 1.0f / lsum;
        const size_t row = qg;
#pragma unroll
        for (int nt = 0; nt < 4; ++nt) {
            uint2 pk;
            pk.x = (u32)f2b(o[nt][0] * inv) | ((u32)f2b(o[nt][1] * inv) << 16);
            pk.y = (u32)f2b(o[nt][2] * inv) | ((u32)f2b(o[nt][3] * inv) << 16);
            *(uint2*)&ctx[row * D_MODEL + h * DK + nt * 16 + kq * 4] = pk;
        }
    };
    wout(oA, laccA[0], qgA);
    wout(oB, laccB[0], qgB);
}

// ---------------------------------------------------------------------------
extern "C" void kernel_launch(void* const* d_in, const int* in_sizes, int n_in,
                              void* d_out, int out_size, void* d_ws, size_t ws_size,
                              hipStream_t stream) {
    const float* x    = (const float*)d_in[0];
    const float* fcos = (const float*)d_in[1];
    const float* fsin = (const float*)d_in[2];
    const float* Wq = (const float*)d_in[4];
    const float* Wk = (const float*)d_in[5];
    const float* Wv = (const float*)d_in[6];
    const float* Wo = (const float*)d_in[7];
    const float* ln1 = (const float*)d_in[8];
    const float* ln2 = (const float*)d_in[9];
    const float* w1 = (const float*)d_in[10];
    const float* w2 = (const float*)d_in[11];
    const float* w3 = (const float*)d_in[12];
    float* out = (float*)d_out;

    char* ws = (char*)d_ws;
    size_t off = 0;
    auto alloc = [&](size_t bytes) -> char* {
        char* p = ws + off;
        off += (bytes + 255) & ~(size_t)255;
        return p;
    };
    u16* hb    = (u16*)alloc((size_t)S_LEN * D_MODEL * 2);
    u16* wqkvt = (u16*)alloc((size_t)QKV_LD * D_MODEL * 2);  // [3072][1024]
    u16* wot   = (u16*)alloc((size_t)D_MODEL * D_MODEL * 2);
    u16* qkvb  = (u16*)alloc((size_t)S_LEN * QKV_LD * 2);    // [4096][3072]
    u16* vt    = (u16*)alloc((size_t)S_LEN * D_MODEL * 2);   // [H][DK][S]
    u16* kpack = (u16*)alloc((size_t)S_LEN * D_MODEL * 2);   // [H][S][DK]
    u16* ctxb  = (u16*)alloc((size_t)S_LEN * D_MODEL * 2);
    float* x2  = (float*)alloc((size_t)S_LEN * D_MODEL * 4);
    u16* h2b   = (u16*)alloc((size_t)S_LEN * D_MODEL * 2);
    u16* w1t   = (u16*)alloc((size_t)HIDP * D_MODEL * 2);    // [2880][1024]
    u16* w3t   = (u16*)alloc((size_t)HIDP * D_MODEL * 2);
    u16* w2t   = (u16*)alloc((size_t)D_MODEL * HIDP * 2);    // [1024][2880]
    u16* ffb   = (u16*)alloc((size_t)S_LEN * HIDP * 2);      // [4096][2880]

    const dim3 tb32(32, 8);

    // weight transposes + rmsnorm(x, ln1), one launch
    prep_k<<<16832, 256, 0, stream>>>(
        Wq, Wk, Wv, Wo, w1, w3, w2,
        wqkvt, wqkvt + (size_t)D_MODEL * D_MODEL,
        wqkvt + (size_t)2 * D_MODEL * D_MODEL, wot, w1t, w3t, w2t,
        x, ln1, hb);

    // QKV = h @ [Wq|Wk|Wv]   (one 4096x3072x1024 GEMM, raw Q/K)
    gemm128<0><<<dim3(QKV_LD / 128, S_LEN / 128), 256, 0, stream>>>(
        hb, D_MODEL, wqkvt, D_MODEL, qkvb, QKV_LD, D_MODEL, nullptr);

    // K packed (+RoPE) + V transposed per head
    packkv_k<<<dim3(S_LEN / 32, DK / 32, NHEAD), tb32, 0, stream>>>(
        qkvb, fcos, fsin, vt, kpack);

    // flash attention (Q RoPE fused; interleaved causal pairing, 512 blocks)
    flash_k<<<dim3(NHEAD, 32), 256, 0, stream>>>(qkvb, vt, kpack, fcos, fsin, ctxb);

    // x2 = x + ctx @ Wo
    gemm64r<<<dim3(D_MODEL / 64, S_LEN / 128), 256, 0, stream>>>(
        ctxb, D_MODEL, wot, D_MODEL, x2, D_MODEL, D_MODEL, x);

    // h2 = rmsnorm(x2, ln2)
    rmsnorm_k<<<S_LEN, 256, 0, stream>>>(x2, ln2, h2b);

    // ff = silu(h2@w1) * (h2@w3)
    gemm_dual96x<<<dim3(HIDP / 96, S_LEN / 128), 256, 0, stream>>>(
        h2b, D_MODEL, w1t, w3t, D_MODEL, ffb, HIDP, D_MODEL);

    // out = x2 + ff @ w2
    gemm64r<<<dim3(D_MODEL / 64, S_LEN / 128), 256, 0, stream>>>(
        ffb, HIDP, w2t, HIDP, out, D_MODEL, HIDP, x2);
}

// Round 7
// 376.106 us; speedup vs baseline: 1.1362x; 1.0154x over previous
//
#include <hip/hip_runtime.h>

#define S_LEN 4096
#define D_MODEL 1024
#define NHEAD 16
#define DK 64
#define HID 2730
#define HIDP 2880
#define QKV_LD 3072

typedef unsigned short u16;
typedef unsigned int u32;
typedef __bf16 bf16x8 __attribute__((ext_vector_type(8)));
typedef float f32x4 __attribute__((ext_vector_type(4)));

#define MFMA16 __builtin_amdgcn_mfma_f32_16x16x32_bf16
// raw v_exp_f32 (2^x): scores bounded (|s| < ~30), no OCML guard code needed
#define EXP2 __builtin_amdgcn_exp2f

__device__ __forceinline__ float b2f(u16 u) {
    return __builtin_bit_cast(float, (u32)u << 16);
}
__device__ __forceinline__ u16 f2b(float f) {
    u32 u = __builtin_bit_cast(u32, f);
    u += 0x7FFF + ((u >> 16) & 1);
    return (u16)(u >> 16);
}
// pack two f32 -> two bf16 (truncate) in one v_perm_b32
__device__ __forceinline__ u32 pk_trunc(float lo, float hi) {
    return __builtin_amdgcn_perm(__builtin_bit_cast(u32, hi),
                                 __builtin_bit_cast(u32, lo), 0x07060302u);
}
// async global->LDS, 16B per lane; dest must be wave-uniform base + lane*16
__device__ __forceinline__ void gll16(const u16* g, u16* l) {
    __builtin_amdgcn_global_load_lds(
        (__attribute__((address_space(1))) void*)(g),
        (__attribute__((address_space(3))) void*)(l),
        16, 0, 0);
}

// ---------------------------------------------------------------------------
// Prep: 7 weight transposes (fp32->bf16, zero-pad) + rmsnorm(x, ln1) in ONE
// launch. Flat grid, 256-thread blocks. Blocks 0..12735 = tcast segments;
// blocks 12736..16831 = rmsnorm rows.  (HIDP = 2880 = 30*96)
// ---------------------------------------------------------------------------
__global__ __launch_bounds__(256)
void prep_k(const float* s0, const float* s1, const float* s2,
            const float* s3, const float* s4, const float* s5,
            const float* s6, u16* d0, u16* d1, u16* d2, u16* d3,
            u16* d4, u16* d5, u16* d6,
            const float* __restrict__ x, const float* __restrict__ ln1,
            u16* __restrict__ hb) {
    __shared__ float t[32][33];
    __shared__ float red[4];
    const int bid = blockIdx.x;
    const int tid = threadIdx.x;

    if (bid >= 12736) {   // ---- rmsnorm path ----
        const int row = bid - 12736;
        const float4 v = ((const float4*)(x + (size_t)row * D_MODEL))[tid];
        float ss = v.x * v.x + v.y * v.y + v.z * v.z + v.w * v.w;
        for (int o = 32; o; o >>= 1) ss += __shfl_down(ss, o);
        if ((tid & 63) == 0) red[tid >> 6] = ss;
        __syncthreads();
        const float tot = red[0] + red[1] + red[2] + red[3];
        const float rs = rsqrtf(tot * (1.0f / D_MODEL) + 1e-6f);
        const float4 wv = ((const float4*)ln1)[tid];
        u16* op = hb + (size_t)row * D_MODEL + tid * 4;
        u32 p0 = (u32)f2b(v.x * rs * wv.x) | ((u32)f2b(v.y * rs * wv.y) << 16);
        u32 p1 = (u32)f2b(v.z * rs * wv.z) | ((u32)f2b(v.w * rs * wv.w) << 16);
        uint2 pk; pk.x = p0; pk.y = p1;
        *(uint2*)op = pk;
        return;
    }

    // ---- transpose path ----
    const float* srcs[7] = {s0, s1, s2, s3, s4, s5, s6};
    u16* dsts[7] = {d0, d1, d2, d3, d4, d5, d6};
    const int RR[7] = {1024, 1024, 1024, 1024, 1024, 1024, 2730};
    const int CC[7] = {1024, 1024, 1024, 1024, 2730, 2730, 1024};
    const int OC[7] = {1024, 1024, 1024, 1024, 1024, 1024, 2880};
    const int XD[7] = {32, 32, 32, 32, 32, 32, 90};

    int seg, start;
    if (bid < 4096)      { seg = bid >> 10; start = seg << 10; }
    else if (bid < 6976) { seg = 4; start = 4096; }
    else if (bid < 9856) { seg = 5; start = 6976; }
    else                 { seg = 6; start = 9856; }
    const int local = bid - start;
    const int bx = local % XD[seg], byy = local / XD[seg];
    const float* in = srcs[seg];
    u16* out = dsts[seg];
    const int R = RR[seg], C = CC[seg], outC = OC[seg];

    const int r0 = byy * 32;
    const int c0 = bx * 32;
    const int tx = tid & 31, ty = tid >> 5;
#pragma unroll
    for (int j = 0; j < 4; ++j) {
        int ir = c0 + ty + j * 8;
        int ic = r0 + tx;
        t[ty + j * 8][tx] = (ir < R && ic < C) ? in[(size_t)ir * C + ic] : 0.0f;
    }
    __syncthreads();
#pragma unroll
    for (int j = 0; j < 4; ++j)
        out[(size_t)(r0 + ty + j * 8) * outC + c0 + tx] = f2b(t[tx][ty + j * 8]);
}

// ---------------------------------------------------------------------------
// RMSNorm (standalone, for x2 -> h2b)
// ---------------------------------------------------------------------------
__global__ __launch_bounds__(256)
void rmsnorm_k(const float* __restrict__ x, const float* __restrict__ w,
               u16* __restrict__ out) {
    const int row = blockIdx.x;
    const int tid = threadIdx.x;
    const float4 v = ((const float4*)(x + (size_t)row * D_MODEL))[tid];
    float ss = v.x * v.x + v.y * v.y + v.z * v.z + v.w * v.w;
    for (int o = 32; o; o >>= 1) ss += __shfl_down(ss, o);
    __shared__ float red[4];
    if ((tid & 63) == 0) red[tid >> 6] = ss;
    __syncthreads();
    const float tot = red[0] + red[1] + red[2] + red[3];
    const float rs = rsqrtf(tot * (1.0f / D_MODEL) + 1e-6f);
    const float4 wv = ((const float4*)w)[tid];
    u16* op = out + (size_t)row * D_MODEL + tid * 4;
    u32 p0 = (u32)f2b(v.x * rs * wv.x) | ((u32)f2b(v.y * rs * wv.y) << 16);
    u32 p1 = (u32)f2b(v.z * rs * wv.z) | ((u32)f2b(v.w * rs * wv.w) << 16);
    uint2 pk; pk.x = p0; pk.y = p1;
    *(uint2*)op = pk;
}

// ---------------------------------------------------------------------------
// Pack K/V per head, K-RoPE fused:
//   kp[h][s][d] = rope(qkv[s][1024 + h*64 + d])
//   vt[h][d][s] = qkv[s][2048 + h*64 + d]
// ---------------------------------------------------------------------------
__global__ __launch_bounds__(256)
void packkv_k(const u16* __restrict__ qkv, const float* __restrict__ fc,
              const float* __restrict__ fs, u16* __restrict__ vt,
              u16* __restrict__ kp) {
    __shared__ u16 t[32][33];
    const int h = blockIdx.z;
    const int t0 = blockIdx.x * 32;
    const int d0 = blockIdx.y * 32;
    const int tx = threadIdx.x, ty = threadIdx.y;
#pragma unroll
    for (int j = 0; j < 4; ++j)
        t[ty + j * 8][tx] =
            qkv[(size_t)(t0 + ty + j * 8) * QKV_LD + 2 * D_MODEL + h * DK + d0 + tx];

    const int id = ty * 32 + tx;
    const int sA = t0 + (id >> 3);
    const int dA = d0 + (id & 7) * 4;
    uint2 kvp = *(const uint2*)(qkv + (size_t)sA * QKV_LD + D_MODEL + h * DK + dA);
    const int fi = sA * 32 + (dA >> 1);
    const float cc0 = fc[fi], ss0 = fs[fi];
    const float cc1 = fc[fi + 1], ss1 = fs[fi + 1];
    auto rpk = [](u32 w, float c, float s) -> u32 {
        const float a = b2f((u16)w), b = b2f((u16)(w >> 16));
        return (u32)f2b(a * c - b * s) | ((u32)f2b(a * s + b * c) << 16);
    };
    kvp.x = rpk(kvp.x, cc0, ss0);
    kvp.y = rpk(kvp.y, cc1, ss1);
    *(uint2*)(kp + ((size_t)h * S_LEN + sA) * DK + dA) = kvp;

    __syncthreads();
#pragma unroll
    for (int j = 0; j < 4; ++j)
        vt[(size_t)h * DK * S_LEN + (size_t)(d0 + ty + j * 8) * S_LEN + t0 + tx] =
            t[tx][ty + j * 8];
}

// ---------------------------------------------------------------------------
// 128x128 GEMM, BK=64 + XOR-swizzled staging (verified round 6).
// ---------------------------------------------------------------------------
template <int EPI>
__global__ __launch_bounds__(256)
void gemm128(const u16* __restrict__ A, int lda, const u16* __restrict__ Bt, int ldb,
             void* __restrict__ C, int ldc, int K, const float* __restrict__ resid) {
    const int m0 = blockIdx.y * 128, n0 = blockIdx.x * 128;
    const int tid = threadIdx.x;
    const int wave = tid >> 6, lane = tid & 63;
    const int wr = wave >> 1, wc = wave & 1;
    const int r16 = lane & 15, kq = lane >> 4;

    __shared__ __align__(16) u16 As[128 * 64];
    __shared__ __align__(16) u16 Bs[128 * 64];

    const int srow = tid >> 3;                       // 0..31
    const int scol = ((tid & 7) ^ (srow & 7)) * 8;   // pre-swizzled source col
    const u16* ag0 = A + (size_t)(m0 +  0 + srow) * lda + scol;
    const u16* ag1 = A + (size_t)(m0 + 32 + srow) * lda + scol;
    const u16* ag2 = A + (size_t)(m0 + 64 + srow) * lda + scol;
    const u16* ag3 = A + (size_t)(m0 + 96 + srow) * lda + scol;
    const u16* bg0 = Bt + (size_t)(n0 +  0 + srow) * ldb + scol;
    const u16* bg1 = Bt + (size_t)(n0 + 32 + srow) * ldb + scol;
    const u16* bg2 = Bt + (size_t)(n0 + 64 + srow) * ldb + scol;
    const u16* bg3 = Bt + (size_t)(n0 + 96 + srow) * ldb + scol;
    u16* const ad = As + tid * 8;
    u16* const bd = Bs + tid * 8;

    f32x4 acc[16];
#pragma unroll
    for (int i = 0; i < 16; ++i) acc[i] = f32x4{0.f, 0.f, 0.f, 0.f};

    const int rsw = r16 & 7;
    for (int k0 = 0; k0 < K; k0 += 64) {
        __syncthreads();
        gll16(ag0 + k0, ad);
        gll16(ag1 + k0, ad + 2048);
        gll16(ag2 + k0, ad + 4096);
        gll16(ag3 + k0, ad + 6144);
        gll16(bg0 + k0, bd);
        gll16(bg1 + k0, bd + 2048);
        gll16(bg2 + k0, bd + 4096);
        gll16(bg3 + k0, bd + 6144);
        __syncthreads();
#pragma unroll
        for (int ks = 0; ks < 2; ++ks) {
            const int slot = (((ks << 2) | kq) ^ rsw) * 8;
            bf16x8 af[4], bf[4];
#pragma unroll
            for (int mt = 0; mt < 4; ++mt)
                af[mt] = *(const bf16x8*)&As[(wr * 64 + mt * 16 + r16) * 64 + slot];
#pragma unroll
            for (int nt = 0; nt < 4; ++nt)
                bf[nt] = *(const bf16x8*)&Bs[(wc * 64 + nt * 16 + r16) * 64 + slot];
#pragma unroll
            for (int mt = 0; mt < 4; ++mt)
#pragma unroll
                for (int nt = 0; nt < 4; ++nt)
                    acc[mt * 4 + nt] = MFMA16(af[mt], bf[nt], acc[mt * 4 + nt], 0, 0, 0);
        }
    }

#pragma unroll
    for (int mt = 0; mt < 4; ++mt) {
#pragma unroll
        for (int nt = 0; nt < 4; ++nt) {
            const int col = n0 + wc * 64 + nt * 16 + r16;
#pragma unroll
            for (int j = 0; j < 4; ++j) {
                const int row = m0 + wr * 64 + mt * 16 + kq * 4 + j;
                if (EPI == 0) {
                    ((u16*)C)[(size_t)row * ldc + col] = f2b(acc[mt * 4 + nt][j]);
                } else {
                    ((float*)C)[(size_t)row * ldc + col] =
                        resid[(size_t)row * ldc + col] + acc[mt * 4 + nt][j];
                }
            }
        }
    }
}

// ---------------------------------------------------------------------------
// 128(M) x 64(N) GEMM + fp32 residual epilogue, BK=64 + XOR-swizzle
// (verified round 6). LDS = 16 + 8 = 24 KB.
// ---------------------------------------------------------------------------
__global__ __launch_bounds__(256)
void gemm64r(const u16* __restrict__ A, int lda, const u16* __restrict__ Bt, int ldb,
             float* __restrict__ C, int ldc, int K, const float* __restrict__ resid) {
    const int m0 = blockIdx.y * 128, n0 = blockIdx.x * 64;
    const int tid = threadIdx.x;
    const int wave = tid >> 6, lane = tid & 63;
    const int r16 = lane & 15, kq = lane >> 4;

    __shared__ __align__(16) u16 As[128 * 64];
    __shared__ __align__(16) u16 Bs[64 * 64];

    const int srow = tid >> 3;
    const int scol = ((tid & 7) ^ (srow & 7)) * 8;
    const u16* ag0 = A + (size_t)(m0 +  0 + srow) * lda + scol;
    const u16* ag1 = A + (size_t)(m0 + 32 + srow) * lda + scol;
    const u16* ag2 = A + (size_t)(m0 + 64 + srow) * lda + scol;
    const u16* ag3 = A + (size_t)(m0 + 96 + srow) * lda + scol;
    const u16* bg0 = Bt + (size_t)(n0 +  0 + srow) * ldb + scol;
    const u16* bg1 = Bt + (size_t)(n0 + 32 + srow) * ldb + scol;
    u16* const ad = As + tid * 8;
    u16* const bd = Bs + tid * 8;

    f32x4 acc[8];
#pragma unroll
    for (int i = 0; i < 8; ++i) acc[i] = f32x4{0.f, 0.f, 0.f, 0.f};

    const int rsw = r16 & 7;
    for (int k0 = 0; k0 < K; k0 += 64) {
        __syncthreads();
        gll16(ag0 + k0, ad);
        gll16(ag1 + k0, ad + 2048);
        gll16(ag2 + k0, ad + 4096);
        gll16(ag3 + k0, ad + 6144);
        gll16(bg0 + k0, bd);
        gll16(bg1 + k0, bd + 2048);
        __syncthreads();
#pragma unroll
        for (int ks = 0; ks < 2; ++ks) {
            const int slot = (((ks << 2) | kq) ^ rsw) * 8;
            bf16x8 af[2], bf[4];
#pragma unroll
            for (int mt = 0; mt < 2; ++mt)
                af[mt] = *(const bf16x8*)&As[(wave * 32 + mt * 16 + r16) * 64 + slot];
#pragma unroll
            for (int nt = 0; nt < 4; ++nt)
                bf[nt] = *(const bf16x8*)&Bs[(nt * 16 + r16) * 64 + slot];
#pragma unroll
            for (int mt = 0; mt < 2; ++mt)
#pragma unroll
                for (int nt = 0; nt < 4; ++nt)
                    acc[mt * 4 + nt] = MFMA16(af[mt], bf[nt], acc[mt * 4 + nt], 0, 0, 0);
        }
    }

#pragma unroll
    for (int mt = 0; mt < 2; ++mt)
#pragma unroll
        for (int nt = 0; nt < 4; ++nt) {
            const int col = n0 + nt * 16 + r16;
#pragma unroll
            for (int j = 0; j < 4; ++j) {
                const int row = m0 + wave * 32 + mt * 16 + kq * 4 + j;
                C[(size_t)row * ldc + col] =
                    resid[(size_t)row * ldc + col] + acc[mt * 4 + nt][j];
            }
        }
}

// ---------------------------------------------------------------------------
// FFN dual GEMM v3: tile 128(M) x 96(N per matrix), BK=64 (verified win).
// ---------------------------------------------------------------------------
__global__ __launch_bounds__(256, 3)
void gemm_dual96x(const u16* __restrict__ A, int lda,
                  const u16* __restrict__ B1, const u16* __restrict__ B3, int ldb,
                  u16* __restrict__ C, int ldc, int K) {
    const int m0 = blockIdx.y * 128, n0 = blockIdx.x * 96;
    const int tid = threadIdx.x;
    const int wave = tid >> 6, lane = tid & 63;
    const int wr = wave >> 1, wc = wave & 1;
    const int r16 = lane & 15, kq = lane >> 4;

    __shared__ __align__(16) u16 As[128 * 64];   // swizzled rows
    __shared__ __align__(16) u16 Bs[192 * 64];   // rows 0-95 = B1, 96-191 = B3

    const int srow = tid >> 3;                       // 0..31 (row within call)
    const int scol = ((tid & 7) ^ (srow & 7)) * 8;   // pre-swizzled source col
    const u16* ag0 = A + (size_t)(m0 +  0 + srow) * lda + scol;
    const u16* ag1 = A + (size_t)(m0 + 32 + srow) * lda + scol;
    const u16* ag2 = A + (size_t)(m0 + 64 + srow) * lda + scol;
    const u16* ag3 = A + (size_t)(m0 + 96 + srow) * lda + scol;
    const u16* bg0 = B1 + (size_t)(n0 +  0 + srow) * ldb + scol;
    const u16* bg1 = B1 + (size_t)(n0 + 32 + srow) * ldb + scol;
    const u16* bg2 = B1 + (size_t)(n0 + 64 + srow) * ldb + scol;
    const u16* bg3 = B3 + (size_t)(n0 +  0 + srow) * ldb + scol;
    const u16* bg4 = B3 + (size_t)(n0 + 32 + srow) * ldb + scol;
    const u16* bg5 = B3 + (size_t)(n0 + 64 + srow) * ldb + scol;
    u16* const ad = As + tid * 8;
    u16* const bd = Bs + tid * 8;

    f32x4 acc1[12], acc3[12];
#pragma unroll
    for (int i = 0; i < 12; ++i) {
        acc1[i] = f32x4{0.f, 0.f, 0.f, 0.f};
        acc3[i] = f32x4{0.f, 0.f, 0.f, 0.f};
    }

    const int rsw = r16 & 7;
    for (int k0 = 0; k0 < K; k0 += 64) {
        __syncthreads();
        gll16(ag0 + k0, ad);
        gll16(ag1 + k0, ad + 2048);
        gll16(ag2 + k0, ad + 4096);
        gll16(ag3 + k0, ad + 6144);
        gll16(bg0 + k0, bd);
        gll16(bg1 + k0, bd + 2048);
        gll16(bg2 + k0, bd + 4096);
        gll16(bg3 + k0, bd + 6144);
        gll16(bg4 + k0, bd + 8192);
        gll16(bg5 + k0, bd + 10240);
        __syncthreads();
#pragma unroll
        for (int ks = 0; ks < 2; ++ks) {
            const int slot = (((ks << 2) | kq) ^ rsw) * 8;
            bf16x8 af[4], b1f[3], b3f[3];
#pragma unroll
            for (int mt = 0; mt < 4; ++mt)
                af[mt] = *(const bf16x8*)&As[(wr * 64 + mt * 16 + r16) * 64 + slot];
#pragma unroll
            for (int nt = 0; nt < 3; ++nt) {
                b1f[nt] = *(const bf16x8*)&Bs[(wc * 48 + nt * 16 + r16) * 64 + slot];
                b3f[nt] = *(const bf16x8*)&Bs[(96 + wc * 48 + nt * 16 + r16) * 64 + slot];
            }
#pragma unroll
            for (int mt = 0; mt < 4; ++mt)
#pragma unroll
                for (int nt = 0; nt < 3; ++nt) {
                    acc1[mt * 3 + nt] = MFMA16(af[mt], b1f[nt], acc1[mt * 3 + nt], 0, 0, 0);
                    acc3[mt * 3 + nt] = MFMA16(af[mt], b3f[nt], acc3[mt * 3 + nt], 0, 0, 0);
                }
        }
    }

#pragma unroll
    for (int mt = 0; mt < 4; ++mt)
#pragma unroll
        for (int nt = 0; nt < 3; ++nt) {
            const int col = n0 + wc * 48 + nt * 16 + r16;
#pragma unroll
            for (int j = 0; j < 4; ++j) {
                const int row = m0 + wr * 64 + mt * 16 + kq * 4 + j;
                const float v1 = acc1[mt * 3 + nt][j];
                const float v3 = acc3[mt * 3 + nt][j];
                const float sig = 1.0f / (1.0f + __expf(-v1));
                C[(size_t)row * ldc + col] = f2b(v1 * sig * v3);
            }
        }
}

// ---------------------------------------------------------------------------
// Flash attention v10: v8 (interleaved causal pairing) + KVBLK=128.
// One barrier + one prefetch point per TWO 64-kv subtiles: barrier/drain
// events per block drop from qb+1 (33..64) to ceil((qb+1)/2) (17..32), and
// the two subtiles' dependency chains are independent -> compiler can
// overlap subtile-1 QK MFMAs with subtile-0 exp2/pack (2x per-iteration
// ILP at the same 8 waves/CU). The 128-tile is stored as two side-by-side
// 64-subtiles in the EXACT current format: tilec, swizzles, and the staging
// pattern are unchanged; only buffer indexing and loop granularity differ.
// LDS = 2*16(K) + 2*16(V) + 8(Ps) = 72 KB -> 2 blocks/CU (same as before:
// grid 512 = 2/CU). gfx950 allows 160 KB/workgroup.
// ---------------------------------------------------------------------------
__global__ __launch_bounds__(256)
void flash_k(const u16* __restrict__ qkv, const u16* __restrict__ vt,
             const u16* __restrict__ kp, const float* __restrict__ fc,
             const float* __restrict__ fs, u16* __restrict__ ctx) {
    const int h = blockIdx.x;
    const int pair = blockIdx.y;       // 0..31
    const int qa = pair, qb = 63 - pair;
    const int tid = threadIdx.x;
    const int wave = tid >> 6, lane = tid & 63;
    const int r16 = lane & 15, kq = lane >> 4;

    __shared__ __align__(16) u16 Kb[2][2 * 64 * 64];   // [buf][sub 64-tile]
    __shared__ __align__(16) u16 Vb[2][2 * 64 * 64];
    __shared__ __align__(16) u16 Ps[4 * 16 * 64];      // per-wave [q][kv]

    const u16* kb = kp + (size_t)h * S_LEN * DK;
    const u16* vb = vt + (size_t)h * DK * S_LEN;
    const int srow = tid >> 3;
    const int lcol = ((tid & 7) ^ (srow & 7)) * 8;
    const int qloc = wave * 16 + r16;
    const int sw = r16 & 7;
    const int c0 = (kq ^ sw) * 8;
    const int c1 = ((4 ^ kq) ^ sw) * 8;
    const int psw = r16 & 14;
    u16* psrow = Ps + wave * 1024 + r16 * 64;

    const float SC = 0.125f * 1.44269504f;
    auto rp = [SC](u32 w, float c, float s) -> u32 {
        const float a = b2f((u16)w), b = b2f((u16)(w >> 16));
        return (u32)f2b((a * c - b * s) * SC) |
               ((u32)f2b((a * s + b * c) * SC) << 16);
    };
    // Q: raw load + RoPE + scale, in registers (for both q-tiles)
    auto loadq = [&](int qglob, bf16x8& q0out, bf16x8& q1out) {
        const u16* qrow = qkv + (size_t)qglob * QKV_LD + h * DK;
        uint4 uq0 = *(const uint4*)(qrow + kq * 8);
        uint4 uq1 = *(const uint4*)(qrow + 32 + kq * 8);
        const float4 c0v = *(const float4*)(fc + qglob * 32 + kq * 4);
        const float4 s0v = *(const float4*)(fs + qglob * 32 + kq * 4);
        const float4 c1v = *(const float4*)(fc + qglob * 32 + 16 + kq * 4);
        const float4 s1v = *(const float4*)(fs + qglob * 32 + 16 + kq * 4);
        uq0.x = rp(uq0.x, c0v.x, s0v.x); uq0.y = rp(uq0.y, c0v.y, s0v.y);
        uq0.z = rp(uq0.z, c0v.z, s0v.z); uq0.w = rp(uq0.w, c0v.w, s0v.w);
        uq1.x = rp(uq1.x, c1v.x, s1v.x); uq1.y = rp(uq1.y, c1v.y, s1v.y);
        uq1.z = rp(uq1.z, c1v.z, s1v.z); uq1.w = rp(uq1.w, c1v.w, s1v.w);
        q0out = __builtin_bit_cast(bf16x8, uq0);
        q1out = __builtin_bit_cast(bf16x8, uq1);
    };
    const int qgA = qa * 64 + qloc;
    const int qgB = qb * 64 + qloc;
    bf16x8 qfA0, qfA1, qfB0, qfB1;
    loadq(qgA, qfA0, qfA1);
    loadq(qgB, qfB0, qfB1);

    f32x4 oA[4], oB[4];
#pragma unroll
    for (int i = 0; i < 4; ++i) {
        oA[i] = f32x4{0.f, 0.f, 0.f, 0.f};
        oB[i] = f32x4{0.f, 0.f, 0.f, 0.f};
    }
    f32x4 laccA = f32x4{0.f, 0.f, 0.f, 0.f};
    f32x4 laccB = f32x4{0.f, 0.f, 0.f, 0.f};
    const uint4 uone = make_uint4(0x3F803F80u, 0x3F803F80u, 0x3F803F80u, 0x3F803F80u);
    const bf16x8 ones = __builtin_bit_cast(bf16x8, uone);

    // per-tile compute: S^T = K.Q^T -> p=2^s (diag-masked on last tile) ->
    // packed P^T via swizzled wave-private Ps -> O^T += V^T@P^T, l += 1@P^T
    auto tilec = [&](const u16* Ks, const u16* Vs, const bf16x8& q0f,
                     const bf16x8& q1f, f32x4 (&o)[4], f32x4& lacc, bool dmask) {
        f32x4 s[4];
#pragma unroll
        for (int nt = 0; nt < 4; ++nt) {
            s[nt] = f32x4{0.f, 0.f, 0.f, 0.f};
            const bf16x8 k0 = *(const bf16x8*)&Ks[(nt * 16 + r16) * 64 + c0];
            s[nt] = MFMA16(k0, q0f, s[nt], 0, 0, 0);
            const bf16x8 k1 = *(const bf16x8*)&Ks[(nt * 16 + r16) * 64 + c1];
            s[nt] = MFMA16(k1, q1f, s[nt], 0, 0, 0);
        }
        float pr[16];
#pragma unroll
        for (int nt = 0; nt < 4; ++nt)
#pragma unroll
            for (int j = 0; j < 4; ++j) pr[nt * 4 + j] = EXP2(s[nt][j]);
        if (dmask) {
#pragma unroll
            for (int nt = 0; nt < 4; ++nt)
#pragma unroll
                for (int j = 0; j < 4; ++j)
                    if ((nt * 16 + kq * 4 + j) > qloc) pr[nt * 4 + j] = 0.f;
        }
#pragma unroll
        for (int nt = 0; nt < 4; ++nt) {
            uint2 pk;
            pk.x = pk_trunc(pr[nt * 4 + 0], pr[nt * 4 + 1]);
            pk.y = pk_trunc(pr[nt * 4 + 2], pr[nt * 4 + 3]);
            *(uint2*)&psrow[((nt * 4 + kq) ^ psw) * 4] = pk;
        }
#pragma unroll
        for (int ks = 0; ks < 2; ++ks) {
            const bf16x8 pf = *(const bf16x8*)&psrow[((8 * ks + 2 * kq) ^ psw) * 4];
            lacc = MFMA16(ones, pf, lacc, 0, 0, 0);
            const int cv = (((ks << 2) ^ kq) ^ sw) * 8;
#pragma unroll
            for (int nt = 0; nt < 4; ++nt) {
                const bf16x8 vf = *(const bf16x8*)&Vs[(nt * 16 + r16) * 64 + cv];
                o[nt] = MFMA16(vf, pf, o[nt], 0, 0, 0);
            }
        }
    };

    // stage one 64-kv tile t into (kd, vd) -- identical pattern to v8
    auto stage = [&](int t, u16* kd, u16* vd) {
        const int tb = t * 64;
#pragma unroll
        for (int i = 0; i < 2; ++i) {
            const int r = srow + i * 32;
            gll16(kb + (size_t)(tb + r) * DK + lcol, kd + tid * 8 + i * 2048);
            gll16(vb + (size_t)r * S_LEN + tb + lcol, vd + tid * 8 + i * 2048);
        }
    };

    // preload tiles 0,1 into buffer 0 (qb >= 32, so tile 1 always exists)
    stage(0, Kb[0], Vb[0]);
    stage(1, Kb[0] + 4096, Vb[0] + 4096);

    const int nT = (qb + 2) >> 1;      // ceil((qb+1)/2) iterations
    for (int T = 0; T < nT; ++T) {
        __syncthreads();   // drains this iteration's buffer; prev buffer free
        const int nb = (T + 1) * 2;
        if (nb <= qb) {    // prefetch tiles nb, nb+1 into the other buffer
            u16* kd = ((T + 1) & 1) ? Kb[1] : Kb[0];
            u16* vd = ((T + 1) & 1) ? Vb[1] : Vb[0];
            stage(nb, kd, vd);
            if (nb + 1 <= qb) stage(nb + 1, kd + 4096, vd + 4096);
        }
        const u16* Ks = (T & 1) ? Kb[1] : Kb[0];
        const u16* Vs = (T & 1) ? Vb[1] : Vb[0];

        // subtile 0: t = 2T (always <= qb since T < nT)
        {
            const int t = 2 * T;
            tilec(Ks, Vs, qfB0, qfB1, oB, laccB, t == qb);
            if (t <= qa) tilec(Ks, Vs, qfA0, qfA1, oA, laccA, t == qa);
        }
        // subtile 1: t = 2T+1 (may exceed qb on the last iteration)
        if (2 * T + 1 <= qb) {
            const int t = 2 * T + 1;
            tilec(Ks + 4096, Vs + 4096, qfB0, qfB1, oB, laccB, t == qb);
            if (t <= qa) tilec(Ks + 4096, Vs + 4096, qfA0, qfA1, oA, laccA, t == qa);
        }
    }

    // l: every lacc element equals the full sum for column q=r16
    auto wout = [&](f32x4 (&o)[4], float lsum, int qg) {
        const float inv = 1.0f / lsum;
        const size_t row = qg;
#pragma unroll
        for (int nt = 0; nt < 4; ++nt) {
            uint2 pk;
            pk.x = (u32)f2b(o[nt][0] * inv) | ((u32)f2b(o[nt][1] * inv) << 16);
            pk.y = (u32)f2b(o[nt][2] * inv) | ((u32)f2b(o[nt][3] * inv) << 16);
            *(uint2*)&ctx[row * D_MODEL + h * DK + nt * 16 + kq * 4] = pk;
        }
    };
    wout(oA, laccA[0], qgA);
    wout(oB, laccB[0], qgB);
}

// ---------------------------------------------------------------------------
extern "C" void kernel_launch(void* const* d_in, const int* in_sizes, int n_in,
                              void* d_out, int out_size, void* d_ws, size_t ws_size,
                              hipStream_t stream) {
    const float* x    = (const float*)d_in[0];
    const float* fcos = (const float*)d_in[1];
    const float* fsin = (const float*)d_in[2];
    const float* Wq = (const float*)d_in[4];
    const float* Wk = (const float*)d_in[5];
    const float* Wv = (const float*)d_in[6];
    const float* Wo = (const float*)d_in[7];
    const float* ln1 = (const float*)d_in[8];
    const float* ln2 = (const float*)d_in[9];
    const float* w1 = (const float*)d_in[10];
    const float* w2 = (const float*)d_in[11];
    const float* w3 = (const float*)d_in[12];
    float* out = (float*)d_out;

    char* ws = (char*)d_ws;
    size_t off = 0;
    auto alloc = [&](size_t bytes) -> char* {
        char* p = ws + off;
        off += (bytes + 255) & ~(size_t)255;
        return p;
    };
    u16* hb    = (u16*)alloc((size_t)S_LEN * D_MODEL * 2);
    u16* wqkvt = (u16*)alloc((size_t)QKV_LD * D_MODEL * 2);  // [3072][1024]
    u16* wot   = (u16*)alloc((size_t)D_MODEL * D_MODEL * 2);
    u16* qkvb  = (u16*)alloc((size_t)S_LEN * QKV_LD * 2);    // [4096][3072]
    u16* vt    = (u16*)alloc((size_t)S_LEN * D_MODEL * 2);   // [H][DK][S]
    u16* kpack = (u16*)alloc((size_t)S_LEN * D_MODEL * 2);   // [H][S][DK]
    u16* ctxb  = (u16*)alloc((size_t)S_LEN * D_MODEL * 2);
    float* x2  = (float*)alloc((size_t)S_LEN * D_MODEL * 4);
    u16* h2b   = (u16*)alloc((size_t)S_LEN * D_MODEL * 2);
    u16* w1t   = (u16*)alloc((size_t)HIDP * D_MODEL * 2);    // [2880][1024]
    u16* w3t   = (u16*)alloc((size_t)HIDP * D_MODEL * 2);
    u16* w2t   = (u16*)alloc((size_t)D_MODEL * HIDP * 2);    // [1024][2880]
    u16* ffb   = (u16*)alloc((size_t)S_LEN * HIDP * 2);      // [4096][2880]

    const dim3 tb32(32, 8);

    // weight transposes + rmsnorm(x, ln1), one launch
    prep_k<<<16832, 256, 0, stream>>>(
        Wq, Wk, Wv, Wo, w1, w3, w2,
        wqkvt, wqkvt + (size_t)D_MODEL * D_MODEL,
        wqkvt + (size_t)2 * D_MODEL * D_MODEL, wot, w1t, w3t, w2t,
        x, ln1, hb);

    // QKV = h @ [Wq|Wk|Wv]   (one 4096x3072x1024 GEMM, raw Q/K)
    gemm128<0><<<dim3(QKV_LD / 128, S_LEN / 128), 256, 0, stream>>>(
        hb, D_MODEL, wqkvt, D_MODEL, qkvb, QKV_LD, D_MODEL, nullptr);

    // K packed (+RoPE) + V transposed per head
    packkv_k<<<dim3(S_LEN / 32, DK / 32, NHEAD), tb32, 0, stream>>>(
        qkvb, fcos, fsin, vt, kpack);

    // flash attention (Q RoPE fused; causal pairing, KVBLK=128, 512 blocks)
    flash_k<<<dim3(NHEAD, 32), 256, 0, stream>>>(qkvb, vt, kpack, fcos, fsin, ctxb);

    // x2 = x + ctx @ Wo
    gemm64r<<<dim3(D_MODEL / 64, S_LEN / 128), 256, 0, stream>>>(
        ctxb, D_MODEL, wot, D_MODEL, x2, D_MODEL, D_MODEL, x);

    // h2 = rmsnorm(x2, ln2)
    rmsnorm_k<<<S_LEN, 256, 0, stream>>>(x2, ln2, h2b);

    // ff = silu(h2@w1) * (h2@w3)
    gemm_dual96x<<<dim3(HIDP / 96, S_LEN / 128), 256, 0, stream>>>(
        h2b, D_MODEL, w1t, w3t, D_MODEL, ffb, HIDP, D_MODEL);

    // out = x2 + ff @ w2
    gemm64r<<<dim3(D_MODEL / 64, S_LEN / 128), 256, 0, stream>>>(
        ffb, HIDP, w2t, HIDP, out, D_MODEL, HIDP, x2);
}